// Round 10
// baseline (282.320 us; speedup 1.0000x reference)
//
#include <hip/hip_runtime.h>

#define N_NODES 20000
#define N_EDGES 320000
#define IN_CH 256
#define HID_CH 512

typedef unsigned short u16;
typedef __attribute__((ext_vector_type(16))) float f32x16;
typedef __attribute__((ext_vector_type(8))) short bf16x8;
typedef __attribute__((ext_vector_type(4))) u16 u16x4;

__device__ __forceinline__ float bf2f(u16 h) { return __uint_as_float((unsigned)h << 16); }
__device__ __forceinline__ u16 f2bf(float f) {  // round-to-nearest-even
    unsigned u = __float_as_uint(f);
    return (u16)((u + 0x7fffu + ((u >> 16) & 1u)) >> 16);
}

// ---------------------------------------------------------------- CSR build
__global__ void count_deg_kernel(const int* __restrict__ dst, int* __restrict__ deg, int E) {
    int i = blockIdx.x * blockDim.x + threadIdx.x;
    if (i < E) atomicAdd(&deg[dst[i]], 1);
}

// single-block scan: row_ptr (exclusive) + dinv = rsqrt(deg+1)
__global__ __launch_bounds__(256) void scan_kernel(const int* __restrict__ deg,
                                                   int* __restrict__ row_ptr,
                                                   float* __restrict__ dinv, int N) {
    __shared__ int sums[256];
    int t = threadIdx.x;
    const int CH = (N + 255) / 256;
    int base = t * CH;
    int s = 0;
    for (int i = 0; i < CH; ++i) {
        int idx = base + i;
        if (idx < N) {
            int d = deg[idx];
            dinv[idx] = rsqrtf((float)d + 1.0f);
            s += d;
        }
    }
    sums[t] = s;
    __syncthreads();
    for (int off = 1; off < 256; off <<= 1) {
        int v = (t >= off) ? sums[t - off] : 0;
        __syncthreads();
        if (t >= off) sums[t] += v;
        __syncthreads();
    }
    int run = (t == 0) ? 0 : sums[t - 1];
    for (int i = 0; i < CH; ++i) {
        int idx = base + i;
        if (idx <= N) row_ptr[idx] = run;
        if (idx < N) run += deg[idx];
    }
}

// bucket-scatter: epair[pos] = {src, bits(dinv[src])}
__global__ void scatter_edges_kernel(const int* __restrict__ src, const int* __restrict__ dst,
                                     const int* __restrict__ row_ptr, int* __restrict__ cursor,
                                     const float* __restrict__ dinv, int2* __restrict__ epair,
                                     int E) {
    int e = blockIdx.x * blockDim.x + threadIdx.x;
    if (e >= E) return;
    int d = dst[e];
    int s = src[e];
    int pos = row_ptr[d] + atomicAdd(&cursor[d], 1);
    epair[pos] = make_int2(s, __float_as_int(dinv[s]));
}

// ---------------------------------------------------------------- conversions
__global__ void f32_to_bf16_kernel(const float* __restrict__ in, u16* __restrict__ out, int n4) {
    int i = blockIdx.x * blockDim.x + threadIdx.x;
    if (i >= n4) return;
    float4 v = ((const float4*)in)[i];
    u16x4 o = {f2bf(v.x), f2bf(v.y), f2bf(v.z), f2bf(v.w)};
    ((u16x4*)out)[i] = o;
}

// both weights: W [K][N] f32 -> Wt hi/lo [N][K] bf16 (LDS-tiled transpose + split)
__global__ __launch_bounds__(256) void convert_w_kernel(const float* __restrict__ W1,
                                                        u16* __restrict__ hi1, u16* __restrict__ lo1,
                                                        const float* __restrict__ W2,
                                                        u16* __restrict__ hi2, u16* __restrict__ lo2) {
    __shared__ float t[64][65];
    int b = blockIdx.x;
    const float* W;
    u16 *hi, *lo;
    int K;
    if (b < 32) { W = W1; hi = hi1; lo = lo1; K = IN_CH; }
    else        { b -= 32; W = W2; hi = hi2; lo = lo2; K = HID_CH; }
    const int N = HID_CH;
    int k0 = (b >> 3) * 64, n0 = (b & 7) * 64;
    int c = threadIdx.x & 63, r4 = threadIdx.x >> 6;
#pragma unroll
    for (int i = 0; i < 16; ++i) {
        int r = i * 4 + r4;
        t[r][c] = W[(size_t)(k0 + r) * N + n0 + c];
    }
    __syncthreads();
#pragma unroll
    for (int i = 0; i < 16; ++i) {
        int n = i * 4 + r4;
        float f = t[c][n];
        u16 hb = f2bf(f);
        size_t o = (size_t)(n0 + n) * K + k0 + c;
        hi[o] = hb;
        lo[o] = f2bf(f - bf2f(hb));
    }
}

// ---------------------------------------------------------------- gather-aggregate (R7 form + epair)
// z[n] = h[n]*dinv[n]^2 + sum_e h[src]*norm_e*dinv[n];  8-edge batched, full-row vector loads
template <int C>
__global__ void gather_agg_kernel(const u16* __restrict__ h, const int2* __restrict__ epair,
                                  const int* __restrict__ row_ptr, const float* __restrict__ dinv,
                                  u16* __restrict__ z_hi, u16* __restrict__ z_lo, int N) {
    constexpr int NV = C / 64;  // u16 per lane per row (4 or 8)
    typedef u16 vec_t __attribute__((ext_vector_type(NV)));
    int wave = (int)((blockIdx.x * blockDim.x + threadIdx.x) >> 6);
    int lane = threadIdx.x & 63;
    if (wave >= N) return;
    int n = wave;
    float dn = dinv[n];
    float self = dn * dn;
    const vec_t* hp = (const vec_t*)h;  // row r at vector index r*64 + lane
    float acc[NV];
    {
        vec_t v = hp[(size_t)n * 64 + lane];
#pragma unroll
        for (int j = 0; j < NV; ++j) acc[j] = bf2f(v[j]) * self;
    }
    int e0 = row_ptr[n], e1 = row_ptr[n + 1];
    int e = e0;
    for (; e + 8 <= e1; e += 8) {
        int2 p[8];
        vec_t w[8];
#pragma unroll
        for (int b = 0; b < 8; ++b) p[b] = epair[e + b];
#pragma unroll
        for (int b = 0; b < 8; ++b) w[b] = hp[(size_t)p[b].x * 64 + lane];
#pragma unroll
        for (int b = 0; b < 8; ++b) {
            float nr = __int_as_float(p[b].y) * dn;
#pragma unroll
            for (int j = 0; j < NV; ++j) acc[j] = fmaf(bf2f(w[b][j]), nr, acc[j]);
        }
    }
    for (; e < e1; ++e) {
        int2 p = epair[e];
        float nr = __int_as_float(p.y) * dn;
        vec_t w = hp[(size_t)p.x * 64 + lane];
#pragma unroll
        for (int j = 0; j < NV; ++j) acc[j] = fmaf(bf2f(w[j]), nr, acc[j]);
    }
    vec_t vh, vl;
#pragma unroll
    for (int j = 0; j < NV; ++j) {
        u16 hb = f2bf(acc[j]);
        vh[j] = hb;
        vl[j] = f2bf(acc[j] - bf2f(hb));
    }
    ((vec_t*)z_hi)[(size_t)n * 64 + lane] = vh;
    ((vec_t*)z_lo)[(size_t)n * 64 + lane] = vl;
}

// ---------------------------------------------------------------- split-bf16 MFMA GEMM (32x32x16)
// C = (Ah+Al)@(Bh+Bl) + bias; B transposed [N][K]. BM=192, BN=128, BK=32; 6 waves
// (3x2 of 64x64 wave tiles, 2x2 sub-tiles of 32x32); dbuf LDS 2x40KB = 80KB -> 2 blocks/CU.
// LDS swizzle (R9 fix): off ^= ((off>>7)&7)<<4 — 3-bit XOR over row-PAIRS, so every 8
// consecutive rows hit all 8 16B bank-positions of a 128B span (R9's 2-bit version gave
// only 8 positions per 8 rows but fragments span 32 rows -> 4-way conflict, 2.58M count).
// Involution with untouched key bits (7-9); staging pre-applies it on the global source.
// Counted-vmcnt (T4), uniform 8 loads/thread; grid 420 <= 512 -> one dispatch round.
template <int K, bool RELU, bool OUT_BF16>
__global__ __launch_bounds__(384, 3) void gemm_mfma_kernel(
        const u16* __restrict__ Ah, const u16* __restrict__ Al, const u16* __restrict__ Bh,
        const u16* __restrict__ Bl, const float* __restrict__ bias, void* __restrict__ Cout,
        int M, int N) {
    // buffer layout (bytes): Ah@0 (12K), Al@12288, Bh@24576 (8K), Bl@32768 -> 40KB/buf
    __shared__ u16 lds[2][20480];
    const int tid = threadIdx.x;
    const int lane = tid & 63;
    const int wid = tid >> 6;  // 0..5

    // bijective XCD-chunked swizzle (m204)
    const int nmt = (M + 191) / 192;
    const int total = nmt * 4;
    int bid = blockIdx.x;
    int q = total >> 3, r = total & 7;
    int xcd = bid & 7, pp = bid >> 3;
    int lin = (xcd < r) ? (xcd * (q + 1) + pp) : (r * (q + 1) + (xcd - r) * q + pp);
    const int bm = (lin >> 2) * 192;
    const int bn = (lin & 3) * 128;

    const int wm = (wid >> 1) * 64;  // 3 wave-rows
    const int wn = (wid & 1) * 64;   // 2 wave-cols

    f32x16 acc[2][2];
#pragma unroll
    for (int i = 0; i < 2; ++i)
#pragma unroll
        for (int j = 0; j < 2; ++j) acc[i][j] = (f32x16)(0.f);

    // ---- staging geometry. Dest chunk d (bytes, linear in plane); source chunk =
    // d ^ (((d>>7)&7)<<4) decoded to (row, slot). Per-thread: A 2 chunks/plane
    // (768 chunks, 384 thr), B 2 chunks/plane via wid&3 (waves 4-5 duplicate 0-1).
    const int dA0 = tid << 4;                 // wave-uniform base wid*1024 + lane*16
    const int dA1 = dA0 + 6144;
    const int dB0 = ((wid & 3) << 11) + ((lane & 63) << 4);
    const int dB1 = dB0 + 1024;
#define SRCOFF(d, row, sb)                          \
    {                                               \
        int o = (d) ^ ((((d) >> 7) & 7) << 4);      \
        row = o >> 6;                               \
        sb = o & 0x30;                              \
    }
    int rA0, sA0, rA1, sA1, rB0, sB0, rB1, sB1;
    SRCOFF(dA0, rA0, sA0)
    SRCOFF(dA1, rA1, sA1)
    SRCOFF(dB0, rB0, sB0)
    SRCOFF(dB1, rB1, sB1)
#undef SRCOFF
    const char* sA0h = (const char*)(Ah + (size_t)min(bm + rA0, M - 1) * K) + sA0;
    const char* sA1h = (const char*)(Ah + (size_t)min(bm + rA1, M - 1) * K) + sA1;
    const char* sA0l = (const char*)(Al + (size_t)min(bm + rA0, M - 1) * K) + sA0;
    const char* sA1l = (const char*)(Al + (size_t)min(bm + rA1, M - 1) * K) + sA1;
    const char* sB0h = (const char*)(Bh + (size_t)(bn + rB0) * K) + sB0;
    const char* sB1h = (const char*)(Bh + (size_t)(bn + rB1) * K) + sB1;
    const char* sB0l = (const char*)(Bl + (size_t)(bn + rB0) * K) + sB0;
    const char* sB1l = (const char*)(Bl + (size_t)(bn + rB1) * K) + sB1;
    // wave-uniform LDS dest bases (HW adds lane*16)
    const int adst0 = (wid << 10);
    const int adst1 = adst0 + 6144;
    const int bdst0 = ((wid & 3) << 11);
    const int bdst1 = bdst0 + 1024;

#define GLL(srcp, dstoff)                                                               \
    __builtin_amdgcn_global_load_lds(                                                   \
        (const __attribute__((address_space(1))) void*)(srcp),                          \
        (__attribute__((address_space(3))) void*)((char*)&lds[buf][0] + (dstoff)), 16, 0, 0)

#define STAGE(bufv, k0)                                                                 \
    do {                                                                                \
        int buf = (bufv);                                                               \
        size_t kb2 = (size_t)(k0) * 2;                                                  \
        GLL(sA0h + kb2, adst0);                                                         \
        GLL(sA1h + kb2, adst1);                                                         \
        GLL(sA0l + kb2, 12288 + adst0);                                                 \
        GLL(sA1l + kb2, 12288 + adst1);                                                 \
        GLL(sB0h + kb2, 24576 + bdst0);                                                 \
        GLL(sB1h + kb2, 24576 + bdst1);                                                 \
        GLL(sB0l + kb2, 32768 + bdst0);                                                 \
        GLL(sB1l + kb2, 32768 + bdst1);                                                 \
    } while (0)

    STAGE(0, 0);

    const int NT = K / 32;
    const int hi = lane >> 5;        // k-half within 16-k step
    const int rl = lane & 31;
#pragma unroll
    for (int t = 0; t < NT; ++t) {
        int cur = t & 1;
        if (t + 1 < NT) {
            STAGE(cur ^ 1, (t + 1) * 32);
            asm volatile("s_waitcnt vmcnt(8)" ::: "memory");  // prev tile's 8 loads done
        } else {
            asm volatile("s_waitcnt vmcnt(0)" ::: "memory");
        }
        __builtin_amdgcn_s_barrier();
        asm volatile("" ::: "memory");

        const char* L = (const char*)&lds[cur][0];
#pragma unroll
        for (int kc = 0; kc < 2; ++kc) {
            int slot = kc * 2 + hi;
            bf16x8 a_h[2], a_l[2], b_h[2], b_l[2];
#pragma unroll
            for (int i = 0; i < 2; ++i) {
                int ra = wm + i * 32 + rl;
                int off = ra * 64 + slot * 16;
                off ^= ((off >> 7) & 7) << 4;
                a_h[i] = *(const bf16x8*)(L + off);
                a_l[i] = *(const bf16x8*)(L + 12288 + off);
            }
#pragma unroll
            for (int j = 0; j < 2; ++j) {
                int rb = wn + j * 32 + rl;
                int off = rb * 64 + slot * 16;
                off ^= ((off >> 7) & 7) << 4;
                b_h[j] = *(const bf16x8*)(L + 24576 + off);
                b_l[j] = *(const bf16x8*)(L + 32768 + off);
            }
#pragma unroll
            for (int i = 0; i < 2; ++i)
#pragma unroll
                for (int j = 0; j < 2; ++j) {
                    acc[i][j] = __builtin_amdgcn_mfma_f32_32x32x16_bf16(a_h[i], b_h[j], acc[i][j], 0, 0, 0);
                    acc[i][j] = __builtin_amdgcn_mfma_f32_32x32x16_bf16(a_l[i], b_h[j], acc[i][j], 0, 0, 0);
                    acc[i][j] = __builtin_amdgcn_mfma_f32_32x32x16_bf16(a_h[i], b_l[j], acc[i][j], 0, 0, 0);
                }
        }
        asm volatile("" ::: "memory");
        __builtin_amdgcn_s_barrier();
    }
#undef STAGE
#undef GLL

    // epilogue: 32x32 C/D layout col=lane&31, row=(reg&3)+8*(reg>>2)+4*(lane>>5) (m74/m101)
#pragma unroll
    for (int j = 0; j < 2; ++j) {
        int gc = bn + wn + j * 32 + rl;
        float bv = bias[gc];
#pragma unroll
        for (int i = 0; i < 2; ++i) {
#pragma unroll
            for (int reg = 0; reg < 16; ++reg) {
                int row = (reg & 3) + 8 * (reg >> 2) + 4 * hi;
                int gr = bm + wm + i * 32 + row;
                if (gr < M) {
                    float v = acc[i][j][reg] + bv;
                    if (RELU) v = fmaxf(v, 0.f);
                    if (OUT_BF16)
                        ((u16*)Cout)[(size_t)gr * N + gc] = f2bf(v);
                    else
                        ((float*)Cout)[(size_t)gr * N + gc] = v;
                }
            }
        }
    }
}

// ---------------------------------------------------------------- launch
extern "C" void kernel_launch(void* const* d_in, const int* in_sizes, int n_in,
                              void* d_out, int out_size, void* d_ws, size_t ws_size,
                              hipStream_t stream) {
    const float* x  = (const float*)d_in[0];
    const int*   ei = (const int*)d_in[1];
    const float* W1 = (const float*)d_in[2];
    const float* b1 = (const float*)d_in[3];
    const float* W2 = (const float*)d_in[4];
    const float* b2 = (const float*)d_in[5];
    const int* src = ei;
    const int* dst = ei + N_EDGES;

    char* ws = (char*)d_ws;
    size_t off = 0;
    auto alloc = [&](size_t bytes) {
        void* p = ws + off;
        off = (off + bytes + 255) & ~(size_t)255;
        return p;
    };
    int*   deg     = (int*)alloc(N_NODES * 4);  // reused as cursor
    int*   row_ptr = (int*)alloc((N_NODES + 1) * 4);
    float* dinv    = (float*)alloc(N_NODES * 4);
    int2*  epair   = (int2*)alloc((size_t)N_EDGES * 8);
    u16*   wt1_hi  = (u16*)alloc((size_t)IN_CH * HID_CH * 2);
    u16*   wt1_lo  = (u16*)alloc((size_t)IN_CH * HID_CH * 2);
    u16*   wt2_hi  = (u16*)alloc((size_t)HID_CH * HID_CH * 2);
    u16*   wt2_lo  = (u16*)alloc((size_t)HID_CH * HID_CH * 2);
    // overlay region: {xb, z1_hi, z1_lo} then {z2_hi, z2_lo}
    char*  R       = (char*)alloc((size_t)N_NODES * HID_CH * 2 * 2);  // 40.96 MB
    u16* xb    = (u16*)R;                                       // [N, 256]
    u16* z1_hi = (u16*)(R + (size_t)N_NODES * IN_CH * 2);       // [N, 256]
    u16* z1_lo = (u16*)(R + (size_t)N_NODES * IN_CH * 4);       // [N, 256]
    u16* z2_hi = (u16*)R;                                       // [N, 512] (over dead xb+z1_hi)
    u16* z2_lo = (u16*)(R + (size_t)N_NODES * HID_CH * 2);      // [N, 512] (over dead z1_lo)
    u16* h1    = (u16*)d_out;  // bf16 h1 scratch in d_out (dead before final GEMM writes)

    // CSR + dinv + epair
    hipMemsetAsync(deg, 0, N_NODES * 4, stream);
    count_deg_kernel<<<(N_EDGES + 255) / 256, 256, 0, stream>>>(dst, deg, N_EDGES);
    scan_kernel<<<1, 256, 0, stream>>>(deg, row_ptr, dinv, N_NODES);
    hipMemsetAsync(deg, 0, N_NODES * 4, stream);  // deg -> cursor
    scatter_edges_kernel<<<(N_EDGES + 255) / 256, 256, 0, stream>>>(src, dst, row_ptr, deg, dinv,
                                                                    epair, N_EDGES);

    // conversions
    f32_to_bf16_kernel<<<(N_NODES * IN_CH / 4 + 255) / 256, 256, 0, stream>>>(
        x, xb, N_NODES * IN_CH / 4);
    convert_w_kernel<<<96, 256, 0, stream>>>(W1, wt1_hi, wt1_lo, W2, wt2_hi, wt2_lo);

    const int NMT = (N_NODES + 191) / 192;  // 105 -> grid 420
    // layer 1: z1 = P @ xb ; h1 = relu(z1 @ W1 + b1)  (bf16 out)
    gather_agg_kernel<IN_CH><<<(N_NODES + 3) / 4, 256, 0, stream>>>(xb, epair, row_ptr, dinv,
                                                                    z1_hi, z1_lo, N_NODES);
    gemm_mfma_kernel<IN_CH, true, true><<<NMT * 4, 384, 0, stream>>>(
        z1_hi, z1_lo, wt1_hi, wt1_lo, b1, h1, N_NODES, HID_CH);

    // layer 2: z2 = P @ h1 ; out = z2 @ W2 + b2  (fp32 out)
    gather_agg_kernel<HID_CH><<<(N_NODES + 3) / 4, 256, 0, stream>>>(h1, epair, row_ptr, dinv,
                                                                     z2_hi, z2_lo, N_NODES);
    gemm_mfma_kernel<HID_CH, false, false><<<NMT * 4, 384, 0, stream>>>(
        z2_hi, z2_lo, wt2_hi, wt2_lo, b2, (float*)d_out, N_NODES, HID_CH);
}

// Round 11
// 254.407 us; speedup vs baseline: 1.1097x; 1.1097x over previous
//
#include <hip/hip_runtime.h>

#define N_NODES 20000
#define N_EDGES 320000
#define IN_CH 256
#define HID_CH 512

typedef unsigned short u16;
typedef __attribute__((ext_vector_type(4))) float f32x4;
typedef __attribute__((ext_vector_type(8))) short bf16x8;
typedef __attribute__((ext_vector_type(4))) u16 u16x4;

__device__ __forceinline__ float bf2f(u16 h) { return __uint_as_float((unsigned)h << 16); }
__device__ __forceinline__ u16 f2bf(float f) {  // round-to-nearest-even
    unsigned u = __float_as_uint(f);
    return (u16)((u + 0x7fffu + ((u >> 16) & 1u)) >> 16);
}

// ---------------------------------------------------------------- CSR build
__global__ void count_deg_kernel(const int* __restrict__ dst, int* __restrict__ deg, int E) {
    int i = blockIdx.x * blockDim.x + threadIdx.x;
    if (i < E) atomicAdd(&deg[dst[i]], 1);
}

// single-block scan: row_ptr (exclusive) + dinv = rsqrt(deg+1)
__global__ __launch_bounds__(256) void scan_kernel(const int* __restrict__ deg,
                                                   int* __restrict__ row_ptr,
                                                   float* __restrict__ dinv, int N) {
    __shared__ int sums[256];
    int t = threadIdx.x;
    const int CH = (N + 255) / 256;
    int base = t * CH;
    int s = 0;
    for (int i = 0; i < CH; ++i) {
        int idx = base + i;
        if (idx < N) {
            int d = deg[idx];
            dinv[idx] = rsqrtf((float)d + 1.0f);
            s += d;
        }
    }
    sums[t] = s;
    __syncthreads();
    for (int off = 1; off < 256; off <<= 1) {
        int v = (t >= off) ? sums[t - off] : 0;
        __syncthreads();
        if (t >= off) sums[t] += v;
        __syncthreads();
    }
    int run = (t == 0) ? 0 : sums[t - 1];
    for (int i = 0; i < CH; ++i) {
        int idx = base + i;
        if (idx <= N) row_ptr[idx] = run;
        if (idx < N) run += deg[idx];
    }
}

// bucket-scatter: epair[pos] = {src, bits(dinv[src])}
__global__ void scatter_edges_kernel(const int* __restrict__ src, const int* __restrict__ dst,
                                     const int* __restrict__ row_ptr, int* __restrict__ cursor,
                                     const float* __restrict__ dinv, int2* __restrict__ epair,
                                     int E) {
    int e = blockIdx.x * blockDim.x + threadIdx.x;
    if (e >= E) return;
    int d = dst[e];
    int s = src[e];
    int pos = row_ptr[d] + atomicAdd(&cursor[d], 1);
    epair[pos] = make_int2(s, __float_as_int(dinv[s]));
}

// ---------------------------------------------------------------- conversions
__global__ void f32_to_bf16_kernel(const float* __restrict__ in, u16* __restrict__ out, int n4) {
    int i = blockIdx.x * blockDim.x + threadIdx.x;
    if (i >= n4) return;
    float4 v = ((const float4*)in)[i];
    u16x4 o = {f2bf(v.x), f2bf(v.y), f2bf(v.z), f2bf(v.w)};
    ((u16x4*)out)[i] = o;
}

// both weights: W [K][N] f32 -> Wt hi/lo [N][K] bf16 (LDS-tiled transpose + split)
__global__ __launch_bounds__(256) void convert_w_kernel(const float* __restrict__ W1,
                                                        u16* __restrict__ hi1, u16* __restrict__ lo1,
                                                        const float* __restrict__ W2,
                                                        u16* __restrict__ hi2, u16* __restrict__ lo2) {
    __shared__ float t[64][65];
    int b = blockIdx.x;
    const float* W;
    u16 *hi, *lo;
    int K;
    if (b < 32) { W = W1; hi = hi1; lo = lo1; K = IN_CH; }
    else        { b -= 32; W = W2; hi = hi2; lo = lo2; K = HID_CH; }
    const int N = HID_CH;
    int k0 = (b >> 3) * 64, n0 = (b & 7) * 64;
    int c = threadIdx.x & 63, r4 = threadIdx.x >> 6;
#pragma unroll
    for (int i = 0; i < 16; ++i) {
        int r = i * 4 + r4;
        t[r][c] = W[(size_t)(k0 + r) * N + n0 + c];
    }
    __syncthreads();
#pragma unroll
    for (int i = 0; i < 16; ++i) {
        int n = i * 4 + r4;
        float f = t[c][n];
        u16 hb = f2bf(f);
        size_t o = (size_t)(n0 + n) * K + k0 + c;
        hi[o] = hb;
        lo[o] = f2bf(f - bf2f(hb));
    }
}

// ---------------------------------------------------------------- gather-aggregate
// z[n] = h[n]*dinv[n]^2 + sum_e h[src]*norm_e*dinv[n]; BATCH-edge batched for MLP;
// emits ONLY the bf16 hi plane (the GEMM's 2-term split no longer needs z_lo).
template <int C, int BATCH>
__global__ __launch_bounds__(256, 4) void gather_agg_kernel(
        const u16* __restrict__ h, const int2* __restrict__ epair,
        const int* __restrict__ row_ptr, const float* __restrict__ dinv,
        u16* __restrict__ z, int N) {
    constexpr int NV = C / 64;  // u16 per lane per row (4 or 8)
    typedef u16 vec_t __attribute__((ext_vector_type(NV)));
    int wave = (int)((blockIdx.x * blockDim.x + threadIdx.x) >> 6);
    int lane = threadIdx.x & 63;
    if (wave >= N) return;
    int n = wave;
    float dn = dinv[n];
    float self = dn * dn;
    const vec_t* hp = (const vec_t*)h;  // row r at vector index r*64 + lane
    float acc[NV];
    {
        vec_t v = hp[(size_t)n * 64 + lane];
#pragma unroll
        for (int j = 0; j < NV; ++j) acc[j] = bf2f(v[j]) * self;
    }
    int e0 = row_ptr[n], e1 = row_ptr[n + 1];
    int e = e0;
    for (; e + BATCH <= e1; e += BATCH) {
        int2 p[BATCH];
        vec_t w[BATCH];
#pragma unroll
        for (int b = 0; b < BATCH; ++b) p[b] = epair[e + b];
#pragma unroll
        for (int b = 0; b < BATCH; ++b) w[b] = hp[(size_t)p[b].x * 64 + lane];
#pragma unroll
        for (int b = 0; b < BATCH; ++b) {
            float nr = __int_as_float(p[b].y) * dn;
#pragma unroll
            for (int j = 0; j < NV; ++j) acc[j] = fmaf(bf2f(w[b][j]), nr, acc[j]);
        }
    }
    for (; e + 4 <= e1; e += 4) {
        int2 p[4];
        vec_t w[4];
#pragma unroll
        for (int b = 0; b < 4; ++b) p[b] = epair[e + b];
#pragma unroll
        for (int b = 0; b < 4; ++b) w[b] = hp[(size_t)p[b].x * 64 + lane];
#pragma unroll
        for (int b = 0; b < 4; ++b) {
            float nr = __int_as_float(p[b].y) * dn;
#pragma unroll
            for (int j = 0; j < NV; ++j) acc[j] = fmaf(bf2f(w[b][j]), nr, acc[j]);
        }
    }
    for (; e < e1; ++e) {
        int2 p = epair[e];
        float nr = __int_as_float(p.y) * dn;
        vec_t w = hp[(size_t)p.x * 64 + lane];
#pragma unroll
        for (int j = 0; j < NV; ++j) acc[j] = fmaf(bf2f(w[j]), nr, acc[j]);
    }
    vec_t vh;
#pragma unroll
    for (int j = 0; j < NV; ++j) vh[j] = f2bf(acc[j]);
    ((vec_t*)z)[(size_t)n * 64 + lane] = vh;
}

// ---------------------------------------------------------------- 2-term split-bf16 MFMA GEMM
// C = A_hi @ (B_hi + B_lo) + bias;  B transposed [N][K].  BM=128, BN=128, BK=32; 8 waves
// (2x4 of 64x32); TRIPLE-buffered LDS (3 x 24KB = 72KB -> 2 blocks/CU, 16 waves/CU).
// 2-deep prefetch: stage(t+2) issued at iter t; vmcnt(6) waits only on loads issued TWO
// compute phases (~800-1200cy) ago >= HBM latency -> the R7-R10 latency stall is covered.
// LDS swizzle: slot ^= (row>>1)&3 within 64B rows (R7-measured: 0 conflicts). Staging:
// 24 distinct 1KB regions / 8 waves = 3 loads/thread, NO duplicate writes (R9/R10's
// swizzle-invariant 2.58M conflict count was duplicated B staging).
template <int K, bool RELU, bool OUT_BF16>
__global__ __launch_bounds__(512, 4) void gemm_mfma_kernel(
        const u16* __restrict__ A, const u16* __restrict__ Bh, const u16* __restrict__ Bl,
        const float* __restrict__ bias, void* __restrict__ Cout, int M, int N) {
    // per buffer (bytes): A@0 (8K), Bh@8192 (8K), Bl@16384 (8K) = 24KB
    __shared__ u16 lds[3][12288];
    const int tid = threadIdx.x;
    const int lane = tid & 63;
    const int wid = tid >> 6;  // 0..7

    // bijective XCD-chunked swizzle (m204)
    const int nmt = (M + 127) / 128;
    const int total = nmt * 4;
    int bid = blockIdx.x;
    int q = total >> 3, r = total & 7;
    int xcd = bid & 7, pp = bid >> 3;
    int lin = (xcd < r) ? (xcd * (q + 1) + pp) : (r * (q + 1) + (xcd - r) * q + pp);
    const int bm = (lin >> 2) * 128;
    const int bn = (lin & 3) * 128;

    const int wm = (wid & 1) * 64;   // 2 wave-rows
    const int wn = (wid >> 1) * 32;  // 4 wave-cols

    f32x4 acc[4][2];
#pragma unroll
    for (int i = 0; i < 4; ++i)
#pragma unroll
        for (int j = 0; j < 2; ++j) acc[i][j] = (f32x4){0.f, 0.f, 0.f, 0.f};

    // staging: per plane 512 chunks of 16B; wave w covers region [w*64, w*64+64) chunks.
    // chunk = w*64+lane -> dest row = w*16 + (lane>>2), dest slot = lane&3; source is
    // pre-swizzled: slot ^ ((row>>1)&3) = (lane&3) ^ ((lane>>3)&3)  (w*16 contributes 0).
    const int srow = (wid << 4) + (lane >> 2);  // 0..127
    const int scb = (((lane & 3) ^ ((lane >> 3) & 3)) << 4);
    const char* srcA  = (const char*)(A  + (size_t)min(bm + srow, M - 1) * K) + scb;
    const char* srcBh = (const char*)(Bh + (size_t)(bn + srow) * K) + scb;
    const char* srcBl = (const char*)(Bl + (size_t)(bn + srow) * K) + scb;
    const int dstoff = wid << 10;  // wave-uniform (HW adds lane*16)

#define GLL(srcp, dstb)                                                                  \
    __builtin_amdgcn_global_load_lds(                                                    \
        (const __attribute__((address_space(1))) void*)(srcp),                           \
        (__attribute__((address_space(3))) void*)((char*)&lds[buf][0] + (dstb)), 16, 0, 0)

#define STAGE(bufv, k0)                                                                  \
    do {                                                                                 \
        int buf = (bufv);                                                                \
        size_t kb2 = (size_t)(k0) * 2;                                                   \
        GLL(srcA + kb2, dstoff);                                                         \
        GLL(srcBh + kb2, 8192 + dstoff);                                                 \
        GLL(srcBl + kb2, 16384 + dstoff);                                                \
    } while (0)

    STAGE(0, 0);
    STAGE(1, 32);

    const int NT = K / 32;
    const int kb = (lane >> 4) << 4;  // fragment k byte-offset within 64B row
#pragma unroll
    for (int t = 0; t < NT; ++t) {
        if (t + 2 < NT) {
            STAGE((t + 2) % 3, (t + 2) * 32);
            asm volatile("s_waitcnt vmcnt(6)" ::: "memory");  // stage-t done; t+1,t+2 in flight
        } else if (t + 1 < NT) {
            asm volatile("s_waitcnt vmcnt(3)" ::: "memory");
        } else {
            asm volatile("s_waitcnt vmcnt(0)" ::: "memory");
        }
        __builtin_amdgcn_s_barrier();   // all waves: buf[t%3] fully populated
        asm volatile("" ::: "memory");

        const char* L = (const char*)&lds[t % 3][0];
        bf16x8 a[4], b_h[2], b_l[2];
#pragma unroll
        for (int i = 0; i < 4; ++i) {
            int ra = wm + i * 16 + (lane & 15);
            int off = ra * 64 + (kb ^ (((ra >> 1) & 3) << 4));
            a[i] = *(const bf16x8*)(L + off);
        }
#pragma unroll
        for (int j = 0; j < 2; ++j) {
            int rb = wn + j * 16 + (lane & 15);
            int off = rb * 64 + (kb ^ (((rb >> 1) & 3) << 4));
            b_h[j] = *(const bf16x8*)(L + 8192 + off);
            b_l[j] = *(const bf16x8*)(L + 16384 + off);
        }
#pragma unroll
        for (int i = 0; i < 4; ++i)
#pragma unroll
            for (int j = 0; j < 2; ++j) {
                acc[i][j] = __builtin_amdgcn_mfma_f32_16x16x32_bf16(a[i], b_h[j], acc[i][j], 0, 0, 0);
                acc[i][j] = __builtin_amdgcn_mfma_f32_16x16x32_bf16(a[i], b_l[j], acc[i][j], 0, 0, 0);
            }
        asm volatile("" ::: "memory");
        __builtin_amdgcn_s_barrier();   // all waves done reading buf[t%3]
    }
#undef STAGE
#undef GLL

    // epilogue: C/D layout col=lane&15, row=(lane>>4)*4+t  (m89/m91 verified)
#pragma unroll
    for (int j = 0; j < 2; ++j) {
        int gc = bn + wn + j * 16 + (lane & 15);
        float bv = bias[gc];
#pragma unroll
        for (int i = 0; i < 4; ++i) {
#pragma unroll
            for (int t = 0; t < 4; ++t) {
                int gr = bm + wm + i * 16 + ((lane >> 4) << 2) + t;
                if (gr < M) {
                    float v = acc[i][j][t] + bv;
                    if (RELU) v = fmaxf(v, 0.f);
                    if (OUT_BF16)
                        ((u16*)Cout)[(size_t)gr * N + gc] = f2bf(v);
                    else
                        ((float*)Cout)[(size_t)gr * N + gc] = v;
                }
            }
        }
    }
}

// ---------------------------------------------------------------- launch
extern "C" void kernel_launch(void* const* d_in, const int* in_sizes, int n_in,
                              void* d_out, int out_size, void* d_ws, size_t ws_size,
                              hipStream_t stream) {
    const float* x  = (const float*)d_in[0];
    const int*   ei = (const int*)d_in[1];
    const float* W1 = (const float*)d_in[2];
    const float* b1 = (const float*)d_in[3];
    const float* W2 = (const float*)d_in[4];
    const float* b2 = (const float*)d_in[5];
    const int* src = ei;
    const int* dst = ei + N_EDGES;

    char* ws = (char*)d_ws;
    size_t off = 0;
    auto alloc = [&](size_t bytes) {
        void* p = ws + off;
        off = (off + bytes + 255) & ~(size_t)255;
        return p;
    };
    int*   deg     = (int*)alloc(N_NODES * 4);  // reused as cursor
    int*   row_ptr = (int*)alloc((N_NODES + 1) * 4);
    float* dinv    = (float*)alloc(N_NODES * 4);
    int2*  epair   = (int2*)alloc((size_t)N_EDGES * 8);
    u16*   wt1_hi  = (u16*)alloc((size_t)IN_CH * HID_CH * 2);
    u16*   wt1_lo  = (u16*)alloc((size_t)IN_CH * HID_CH * 2);
    u16*   wt2_hi  = (u16*)alloc((size_t)HID_CH * HID_CH * 2);
    u16*   wt2_lo  = (u16*)alloc((size_t)HID_CH * HID_CH * 2);
    u16*   xb      = (u16*)alloc((size_t)N_NODES * IN_CH * 2);   // [N, 256] bf16
    u16*   z1      = (u16*)alloc((size_t)N_NODES * IN_CH * 2);   // [N, 256] bf16 (hi only)
    u16*   z2      = (u16*)alloc((size_t)N_NODES * HID_CH * 2);  // [N, 512] bf16 (hi only)
    u16*   h1      = (u16*)d_out;  // bf16 h1 scratch in d_out (dead before final GEMM writes)

    // CSR + dinv + epair
    hipMemsetAsync(deg, 0, N_NODES * 4, stream);
    count_deg_kernel<<<(N_EDGES + 255) / 256, 256, 0, stream>>>(dst, deg, N_EDGES);
    scan_kernel<<<1, 256, 0, stream>>>(deg, row_ptr, dinv, N_NODES);
    hipMemsetAsync(deg, 0, N_NODES * 4, stream);  // deg -> cursor
    scatter_edges_kernel<<<(N_EDGES + 255) / 256, 256, 0, stream>>>(src, dst, row_ptr, deg, dinv,
                                                                    epair, N_EDGES);

    // conversions
    f32_to_bf16_kernel<<<(N_NODES * IN_CH / 4 + 255) / 256, 256, 0, stream>>>(
        x, xb, N_NODES * IN_CH / 4);
    convert_w_kernel<<<96, 256, 0, stream>>>(W1, wt1_hi, wt1_lo, W2, wt2_hi, wt2_lo);

    const int NMT = (N_NODES + 127) / 128;  // 157 -> grid 628
    // layer 1: z1 = P @ xb ; h1 = relu(z1 @ (W1h+W1l) + b1)  (bf16 out)
    gather_agg_kernel<IN_CH, 16><<<(N_NODES + 3) / 4, 256, 0, stream>>>(xb, epair, row_ptr, dinv,
                                                                        z1, N_NODES);
    gemm_mfma_kernel<IN_CH, true, true><<<NMT * 4, 512, 0, stream>>>(
        z1, wt1_hi, wt1_lo, b1, h1, N_NODES, HID_CH);

    // layer 2: z2 = P @ h1 ; out = z2 @ (W2h+W2l) + b2  (fp32 out)
    gather_agg_kernel<HID_CH, 12><<<(N_NODES + 3) / 4, 256, 0, stream>>>(h1, epair, row_ptr, dinv,
                                                                         z2, N_NODES);
    gemm_mfma_kernel<HID_CH, false, false><<<NMT * 4, 512, 0, stream>>>(
        z2, wt2_hi, wt2_lo, b2, (float*)d_out, N_NODES, HID_CH);
}

// Round 12
// 248.951 us; speedup vs baseline: 1.1340x; 1.0219x over previous
//
#include <hip/hip_runtime.h>

#define N_NODES 20000
#define N_EDGES 320000
#define IN_CH 256
#define HID_CH 512

typedef unsigned short u16;
typedef __attribute__((ext_vector_type(4))) float f32x4;
typedef __attribute__((ext_vector_type(8))) short bf16x8;
typedef __attribute__((ext_vector_type(4))) u16 u16x4;
typedef __attribute__((ext_vector_type(8))) u16 u16x8;

__device__ __forceinline__ float bf2f(u16 h) { return __uint_as_float((unsigned)h << 16); }
__device__ __forceinline__ u16 f2bf(float f) {  // round-to-nearest-even
    unsigned u = __float_as_uint(f);
    return (u16)((u + 0x7fffu + ((u >> 16) & 1u)) >> 16);
}

// ---------------------------------------------------------------- CSR build
__global__ void count_deg_kernel(const int* __restrict__ dst, int* __restrict__ deg, int E) {
    int i = blockIdx.x * blockDim.x + threadIdx.x;
    if (i < E) atomicAdd(&deg[dst[i]], 1);
}

// single-block scan: row_ptr (exclusive) + dinv = rsqrt(deg+1)
__global__ __launch_bounds__(256) void scan_kernel(const int* __restrict__ deg,
                                                   int* __restrict__ row_ptr,
                                                   float* __restrict__ dinv, int N) {
    __shared__ int sums[256];
    int t = threadIdx.x;
    const int CH = (N + 255) / 256;
    int base = t * CH;
    int s = 0;
    for (int i = 0; i < CH; ++i) {
        int idx = base + i;
        if (idx < N) {
            int d = deg[idx];
            dinv[idx] = rsqrtf((float)d + 1.0f);
            s += d;
        }
    }
    sums[t] = s;
    __syncthreads();
    for (int off = 1; off < 256; off <<= 1) {
        int v = (t >= off) ? sums[t - off] : 0;
        __syncthreads();
        if (t >= off) sums[t] += v;
        __syncthreads();
    }
    int run = (t == 0) ? 0 : sums[t - 1];
    for (int i = 0; i < CH; ++i) {
        int idx = base + i;
        if (idx <= N) row_ptr[idx] = run;
        if (idx < N) run += deg[idx];
    }
}

// bucket-scatter: epair[pos] = {src, bits(dinv[src])}
__global__ void scatter_edges_kernel(const int* __restrict__ src, const int* __restrict__ dst,
                                     const int* __restrict__ row_ptr, int* __restrict__ cursor,
                                     const float* __restrict__ dinv, int2* __restrict__ epair,
                                     int E) {
    int e = blockIdx.x * blockDim.x + threadIdx.x;
    if (e >= E) return;
    int d = dst[e];
    int s = src[e];
    int pos = row_ptr[d] + atomicAdd(&cursor[d], 1);
    epair[pos] = make_int2(s, __float_as_int(dinv[s]));
}

// ---------------------------------------------------------------- conversions
__global__ void f32_to_bf16_kernel(const float* __restrict__ in, u16* __restrict__ out, int n4) {
    int i = blockIdx.x * blockDim.x + threadIdx.x;
    if (i >= n4) return;
    float4 v = ((const float4*)in)[i];
    u16x4 o = {f2bf(v.x), f2bf(v.y), f2bf(v.z), f2bf(v.w)};
    ((u16x4*)out)[i] = o;
}

// both weights: W [K][N] f32 -> Wt hi/lo [N][K] bf16 (LDS-tiled transpose + split)
__global__ __launch_bounds__(256) void convert_w_kernel(const float* __restrict__ W1,
                                                        u16* __restrict__ hi1, u16* __restrict__ lo1,
                                                        const float* __restrict__ W2,
                                                        u16* __restrict__ hi2, u16* __restrict__ lo2) {
    __shared__ float t[64][65];
    int b = blockIdx.x;
    const float* W;
    u16 *hi, *lo;
    int K;
    if (b < 32) { W = W1; hi = hi1; lo = lo1; K = IN_CH; }
    else        { b -= 32; W = W2; hi = hi2; lo = lo2; K = HID_CH; }
    const int N = HID_CH;
    int k0 = (b >> 3) * 64, n0 = (b & 7) * 64;
    int c = threadIdx.x & 63, r4 = threadIdx.x >> 6;
#pragma unroll
    for (int i = 0; i < 16; ++i) {
        int r = i * 4 + r4;
        t[r][c] = W[(size_t)(k0 + r) * N + n0 + c];
    }
    __syncthreads();
#pragma unroll
    for (int i = 0; i < 16; ++i) {
        int n = i * 4 + r4;
        float f = t[c][n];
        u16 hb = f2bf(f);
        size_t o = (size_t)(n0 + n) * K + k0 + c;
        hi[o] = hb;
        lo[o] = f2bf(f - bf2f(hb));
    }
}

// ---------------------------------------------------------------- XCD-sliced VECTOR gather
// z[n] = h[n]*dinv[n]^2 + sum_e h[src]*norm_e*dinv[n]
// Slice = 64 ch = 2.56 MB table slice (< 4MB XCD L2), pinned to XCD via bid&7 (mechanism
// VERIFIED in R8: FETCH 143->23 MB). Unlike R8 (1ch/lane scalar loads -> issue-bound),
// a wave = 8 groups x 8 lanes: group g loads edge (e+g)'s slice as ONE u16x8 per lane
// (16B/lane, 128B/edge) -> 16 edges in flight with 2 loads/lane/iter. Epilogue:
// shfl_xor(8/16/32) cross-group reduce + self term + 128B write by group 0.
template <int C, int SLICES>
__global__ __launch_bounds__(256) void gather_agg_kernel(
        const u16* __restrict__ h, const int2* __restrict__ epair,
        const int* __restrict__ row_ptr, const float* __restrict__ dinv,
        u16* __restrict__ z, int N) {
    int bid = blockIdx.x;
    int nb, s;
    if (SLICES == 8) {          // slice = XCD
        nb = bid >> 3;
        s = bid & 7;
    } else {                    // SLICES == 4: slice on XCD pair {2s,2s+1}
        nb = (bid >> 3) * 2 + (bid & 1);
        s = (bid & 7) >> 1;
    }
    int wid = threadIdx.x >> 6;
    int lane = threadIdx.x & 63;
    int n = nb * 4 + wid;
    if (n >= N) return;
    int g = lane >> 3;   // edge group 0..7
    int u = lane & 7;    // 8 ch of the slice per lane
    float dn = dinv[n];
    const u16* hbase = h + s * 64 + u * 8;  // + row*C
    float acc[8] = {0.f, 0.f, 0.f, 0.f, 0.f, 0.f, 0.f, 0.f};
    int e0 = row_ptr[n], e1 = row_ptr[n + 1];
    for (int e = e0; e < e1; e += 16) {
        int i0 = e + g, i1 = e + 8 + g;
        int2 p0 = epair[min(i0, e1 - 1)];
        int2 p1 = epair[min(i1, e1 - 1)];
        float n0 = (i0 < e1) ? __int_as_float(p0.y) * dn : 0.f;
        float n1 = (i1 < e1) ? __int_as_float(p1.y) * dn : 0.f;
        u16x8 w0 = *(const u16x8*)(hbase + (size_t)p0.x * C);
        u16x8 w1 = *(const u16x8*)(hbase + (size_t)p1.x * C);
#pragma unroll
        for (int j = 0; j < 8; ++j) acc[j] = fmaf(bf2f(w0[j]), n0, acc[j]);
#pragma unroll
        for (int j = 0; j < 8; ++j) acc[j] = fmaf(bf2f(w1[j]), n1, acc[j]);
    }
    // reduce across the 8 edge-groups (lanes strided by 8)
#pragma unroll
    for (int m = 8; m < 64; m <<= 1) {
#pragma unroll
        for (int j = 0; j < 8; ++j) acc[j] += __shfl_xor(acc[j], m, 64);
    }
    // self-loop term
    float sf = dn * dn;
    u16x8 ws = *(const u16x8*)(hbase + (size_t)n * C);
#pragma unroll
    for (int j = 0; j < 8; ++j) acc[j] = fmaf(bf2f(ws[j]), sf, acc[j]);
    if (g == 0) {
        u16x8 vh;
#pragma unroll
        for (int j = 0; j < 8; ++j) vh[j] = f2bf(acc[j]);
        *(u16x8*)(z + (size_t)n * C + s * 64 + u * 8) = vh;
    }
}

// ---------------------------------------------------------------- 2-term split-bf16 MFMA GEMM
// C = A_hi @ (B_hi + B_lo) + bias;  B transposed [N][K].  BM=128, BN=128, BK=32; 8 waves
// (2x4 of 64x32); TRIPLE-buffered LDS (3 x 24KB = 72KB -> 2 blocks/CU, 16 waves/CU).
// 2-deep prefetch: stage(t+2) issued at iter t; vmcnt(6) waits only on loads issued TWO
// compute phases ago. LDS swizzle: slot ^= (row>>1)&3 (R7-measured: 0 conflicts).
template <int K, bool RELU, bool OUT_BF16>
__global__ __launch_bounds__(512, 4) void gemm_mfma_kernel(
        const u16* __restrict__ A, const u16* __restrict__ Bh, const u16* __restrict__ Bl,
        const float* __restrict__ bias, void* __restrict__ Cout, int M, int N) {
    // per buffer (bytes): A@0 (8K), Bh@8192 (8K), Bl@16384 (8K) = 24KB
    __shared__ u16 lds[3][12288];
    const int tid = threadIdx.x;
    const int lane = tid & 63;
    const int wid = tid >> 6;  // 0..7

    // bijective XCD-chunked swizzle (m204)
    const int nmt = (M + 127) / 128;
    const int total = nmt * 4;
    int bid = blockIdx.x;
    int q = total >> 3, r = total & 7;
    int xcd = bid & 7, pp = bid >> 3;
    int lin = (xcd < r) ? (xcd * (q + 1) + pp) : (r * (q + 1) + (xcd - r) * q + pp);
    const int bm = (lin >> 2) * 128;
    const int bn = (lin & 3) * 128;

    const int wm = (wid & 1) * 64;   // 2 wave-rows
    const int wn = (wid >> 1) * 32;  // 4 wave-cols

    f32x4 acc[4][2];
#pragma unroll
    for (int i = 0; i < 4; ++i)
#pragma unroll
        for (int j = 0; j < 2; ++j) acc[i][j] = (f32x4){0.f, 0.f, 0.f, 0.f};

    // staging: per plane 512 chunks of 16B; wave w covers region [w*64, w*64+64) chunks.
    const int srow = (wid << 4) + (lane >> 2);  // 0..127
    const int scb = (((lane & 3) ^ ((lane >> 3) & 3)) << 4);
    const char* srcA  = (const char*)(A  + (size_t)min(bm + srow, M - 1) * K) + scb;
    const char* srcBh = (const char*)(Bh + (size_t)(bn + srow) * K) + scb;
    const char* srcBl = (const char*)(Bl + (size_t)(bn + srow) * K) + scb;
    const int dstoff = wid << 10;  // wave-uniform (HW adds lane*16)

#define GLL(srcp, dstb)                                                                  \
    __builtin_amdgcn_global_load_lds(                                                    \
        (const __attribute__((address_space(1))) void*)(srcp),                           \
        (__attribute__((address_space(3))) void*)((char*)&lds[buf][0] + (dstb)), 16, 0, 0)

#define STAGE(bufv, k0)                                                                  \
    do {                                                                                 \
        int buf = (bufv);                                                                \
        size_t kb2 = (size_t)(k0) * 2;                                                   \
        GLL(srcA + kb2, dstoff);                                                         \
        GLL(srcBh + kb2, 8192 + dstoff);                                                 \
        GLL(srcBl + kb2, 16384 + dstoff);                                                \
    } while (0)

    STAGE(0, 0);
    STAGE(1, 32);

    const int NT = K / 32;
    const int kb = (lane >> 4) << 4;  // fragment k byte-offset within 64B row
#pragma unroll
    for (int t = 0; t < NT; ++t) {
        if (t + 2 < NT) {
            STAGE((t + 2) % 3, (t + 2) * 32);
            asm volatile("s_waitcnt vmcnt(6)" ::: "memory");  // stage-t done; t+1,t+2 in flight
        } else if (t + 1 < NT) {
            asm volatile("s_waitcnt vmcnt(3)" ::: "memory");
        } else {
            asm volatile("s_waitcnt vmcnt(0)" ::: "memory");
        }
        __builtin_amdgcn_s_barrier();   // all waves: buf[t%3] fully populated
        asm volatile("" ::: "memory");

        const char* L = (const char*)&lds[t % 3][0];
        bf16x8 a[4], b_h[2], b_l[2];
#pragma unroll
        for (int i = 0; i < 4; ++i) {
            int ra = wm + i * 16 + (lane & 15);
            int off = ra * 64 + (kb ^ (((ra >> 1) & 3) << 4));
            a[i] = *(const bf16x8*)(L + off);
        }
#pragma unroll
        for (int j = 0; j < 2; ++j) {
            int rb = wn + j * 16 + (lane & 15);
            int off = rb * 64 + (kb ^ (((rb >> 1) & 3) << 4));
            b_h[j] = *(const bf16x8*)(L + 8192 + off);
            b_l[j] = *(const bf16x8*)(L + 16384 + off);
        }
#pragma unroll
        for (int i = 0; i < 4; ++i)
#pragma unroll
            for (int j = 0; j < 2; ++j) {
                acc[i][j] = __builtin_amdgcn_mfma_f32_16x16x32_bf16(a[i], b_h[j], acc[i][j], 0, 0, 0);
                acc[i][j] = __builtin_amdgcn_mfma_f32_16x16x32_bf16(a[i], b_l[j], acc[i][j], 0, 0, 0);
            }
        asm volatile("" ::: "memory");
        __builtin_amdgcn_s_barrier();   // all waves done reading buf[t%3]
    }
#undef STAGE
#undef GLL

    // epilogue: C/D layout col=lane&15, row=(lane>>4)*4+t  (m89/m91 verified)
#pragma unroll
    for (int j = 0; j < 2; ++j) {
        int gc = bn + wn + j * 16 + (lane & 15);
        float bv = bias[gc];
#pragma unroll
        for (int i = 0; i < 4; ++i) {
#pragma unroll
            for (int t = 0; t < 4; ++t) {
                int gr = bm + wm + i * 16 + ((lane >> 4) << 2) + t;
                if (gr < M) {
                    float v = acc[i][j][t] + bv;
                    if (RELU) v = fmaxf(v, 0.f);
                    if (OUT_BF16)
                        ((u16*)Cout)[(size_t)gr * N + gc] = f2bf(v);
                    else
                        ((float*)Cout)[(size_t)gr * N + gc] = v;
                }
            }
        }
    }
}

// ---------------------------------------------------------------- launch
extern "C" void kernel_launch(void* const* d_in, const int* in_sizes, int n_in,
                              void* d_out, int out_size, void* d_ws, size_t ws_size,
                              hipStream_t stream) {
    const float* x  = (const float*)d_in[0];
    const int*   ei = (const int*)d_in[1];
    const float* W1 = (const float*)d_in[2];
    const float* b1 = (const float*)d_in[3];
    const float* W2 = (const float*)d_in[4];
    const float* b2 = (const float*)d_in[5];
    const int* src = ei;
    const int* dst = ei + N_EDGES;

    char* ws = (char*)d_ws;
    size_t off = 0;
    auto alloc = [&](size_t bytes) {
        void* p = ws + off;
        off = (off + bytes + 255) & ~(size_t)255;
        return p;
    };
    int*   deg     = (int*)alloc(N_NODES * 4);  // reused as cursor
    int*   row_ptr = (int*)alloc((N_NODES + 1) * 4);
    float* dinv    = (float*)alloc(N_NODES * 4);
    int2*  epair   = (int2*)alloc((size_t)N_EDGES * 8);
    u16*   wt1_hi  = (u16*)alloc((size_t)IN_CH * HID_CH * 2);
    u16*   wt1_lo  = (u16*)alloc((size_t)IN_CH * HID_CH * 2);
    u16*   wt2_hi  = (u16*)alloc((size_t)HID_CH * HID_CH * 2);
    u16*   wt2_lo  = (u16*)alloc((size_t)HID_CH * HID_CH * 2);
    u16*   xb      = (u16*)alloc((size_t)N_NODES * IN_CH * 2);   // [N, 256] bf16
    u16*   z1      = (u16*)alloc((size_t)N_NODES * IN_CH * 2);   // [N, 256] bf16 (hi only)
    u16*   z2      = (u16*)alloc((size_t)N_NODES * HID_CH * 2);  // [N, 512] bf16 (hi only)
    u16*   h1      = (u16*)d_out;  // bf16 h1 scratch in d_out (dead before final GEMM writes)

    // CSR + dinv + epair
    hipMemsetAsync(deg, 0, N_NODES * 4, stream);
    count_deg_kernel<<<(N_EDGES + 255) / 256, 256, 0, stream>>>(dst, deg, N_EDGES);
    scan_kernel<<<1, 256, 0, stream>>>(deg, row_ptr, dinv, N_NODES);
    hipMemsetAsync(deg, 0, N_NODES * 4, stream);  // deg -> cursor
    scatter_edges_kernel<<<(N_EDGES + 255) / 256, 256, 0, stream>>>(src, dst, row_ptr, deg, dinv,
                                                                    epair, N_EDGES);

    // conversions
    f32_to_bf16_kernel<<<(N_NODES * IN_CH / 4 + 255) / 256, 256, 0, stream>>>(
        x, xb, N_NODES * IN_CH / 4);
    convert_w_kernel<<<96, 256, 0, stream>>>(W1, wt1_hi, wt1_lo, W2, wt2_hi, wt2_lo);

    const int NMT = (N_NODES + 127) / 128;  // 157 -> grid 628
    // layer 1: z1 = P @ xb (4 slices on XCD pairs) ; h1 = relu(z1 @ (W1h+W1l) + b1) (bf16 out)
    gather_agg_kernel<IN_CH, 4><<<(N_NODES / 4 / 2) * 8, 256, 0, stream>>>(
        xb, epair, row_ptr, dinv, z1, N_NODES);
    gemm_mfma_kernel<IN_CH, true, true><<<NMT * 4, 512, 0, stream>>>(
        z1, wt1_hi, wt1_lo, b1, h1, N_NODES, HID_CH);

    // layer 2: z2 = P @ h1 (8 slices, one per XCD) ; out = z2 @ (W2h+W2l) + b2 (fp32 out)
    gather_agg_kernel<HID_CH, 8><<<(N_NODES / 4) * 8, 256, 0, stream>>>(
        h1, epair, row_ptr, dinv, z2, N_NODES);
    gemm_mfma_kernel<HID_CH, false, false><<<NMT * 4, 512, 0, stream>>>(
        z2, wt2_hi, wt2_lo, b2, (float*)d_out, N_NODES, HID_CH);
}

// Round 13
// 217.004 us; speedup vs baseline: 1.3010x; 1.1472x over previous
//
#include <hip/hip_runtime.h>

#define N_NODES 20000
#define N_EDGES 320000
#define IN_CH 256
#define HID_CH 512

typedef unsigned short u16;
typedef __attribute__((ext_vector_type(4))) float f32x4;
typedef __attribute__((ext_vector_type(8))) short bf16x8;
typedef __attribute__((ext_vector_type(4))) u16 u16x4;
typedef __attribute__((ext_vector_type(8))) u16 u16x8;

__device__ __forceinline__ float bf2f(u16 h) { return __uint_as_float((unsigned)h << 16); }
__device__ __forceinline__ u16 f2bf(float f) {  // round-to-nearest-even
    unsigned u = __float_as_uint(f);
    return (u16)((u + 0x7fffu + ((u >> 16) & 1u)) >> 16);
}

// ---------------------------------------------------------------- CSR build
__global__ void count_deg_kernel(const int* __restrict__ dst, int* __restrict__ deg, int E) {
    int i = blockIdx.x * blockDim.x + threadIdx.x;
    if (i < E) atomicAdd(&deg[dst[i]], 1);
}

// single-block scan: row_ptr (exclusive) + dinv = rsqrt(deg+1)
__global__ __launch_bounds__(256) void scan_kernel(const int* __restrict__ deg,
                                                   int* __restrict__ row_ptr,
                                                   float* __restrict__ dinv, int N) {
    __shared__ int sums[256];
    int t = threadIdx.x;
    const int CH = (N + 255) / 256;
    int base = t * CH;
    int s = 0;
    for (int i = 0; i < CH; ++i) {
        int idx = base + i;
        if (idx < N) {
            int d = deg[idx];
            dinv[idx] = rsqrtf((float)d + 1.0f);
            s += d;
        }
    }
    sums[t] = s;
    __syncthreads();
    for (int off = 1; off < 256; off <<= 1) {
        int v = (t >= off) ? sums[t - off] : 0;
        __syncthreads();
        if (t >= off) sums[t] += v;
        __syncthreads();
    }
    int run = (t == 0) ? 0 : sums[t - 1];
    for (int i = 0; i < CH; ++i) {
        int idx = base + i;
        if (idx <= N) row_ptr[idx] = run;
        if (idx < N) run += deg[idx];
    }
}

// bucket-scatter: epair[pos] = {src, bits(dinv[src])}
__global__ void scatter_edges_kernel(const int* __restrict__ src, const int* __restrict__ dst,
                                     const int* __restrict__ row_ptr, int* __restrict__ cursor,
                                     const float* __restrict__ dinv, int2* __restrict__ epair,
                                     int E) {
    int e = blockIdx.x * blockDim.x + threadIdx.x;
    if (e >= E) return;
    int d = dst[e];
    int s = src[e];
    int pos = row_ptr[d] + atomicAdd(&cursor[d], 1);
    epair[pos] = make_int2(s, __float_as_int(dinv[s]));
}

// ---------------------------------------------------------------- conversions
__global__ void f32_to_bf16_kernel(const float* __restrict__ in, u16* __restrict__ out, int n4) {
    int i = blockIdx.x * blockDim.x + threadIdx.x;
    if (i >= n4) return;
    float4 v = ((const float4*)in)[i];
    u16x4 o = {f2bf(v.x), f2bf(v.y), f2bf(v.z), f2bf(v.w)};
    ((u16x4*)out)[i] = o;
}

// both weights: W [K][N] f32 -> Wt hi/lo [N][K] bf16 (LDS-tiled transpose + split)
__global__ __launch_bounds__(256) void convert_w_kernel(const float* __restrict__ W1,
                                                        u16* __restrict__ hi1, u16* __restrict__ lo1,
                                                        const float* __restrict__ W2,
                                                        u16* __restrict__ hi2, u16* __restrict__ lo2) {
    __shared__ float t[64][65];
    int b = blockIdx.x;
    const float* W;
    u16 *hi, *lo;
    int K;
    if (b < 32) { W = W1; hi = hi1; lo = lo1; K = IN_CH; }
    else        { b -= 32; W = W2; hi = hi2; lo = lo2; K = HID_CH; }
    const int N = HID_CH;
    int k0 = (b >> 3) * 64, n0 = (b & 7) * 64;
    int c = threadIdx.x & 63, r4 = threadIdx.x >> 6;
#pragma unroll
    for (int i = 0; i < 16; ++i) {
        int r = i * 4 + r4;
        t[r][c] = W[(size_t)(k0 + r) * N + n0 + c];
    }
    __syncthreads();
#pragma unroll
    for (int i = 0; i < 16; ++i) {
        int n = i * 4 + r4;
        float f = t[c][n];
        u16 hb = f2bf(f);
        size_t o = (size_t)(n0 + n) * K + k0 + c;
        hi[o] = hb;
        lo[o] = f2bf(f - bf2f(hb));
    }
}

// ---------------------------------------------------------------- XCD-sliced gather, group-per-node
// z[n] = h[n]*dinv[n]^2 + sum_e h[src]*norm_e*dinv[n]
// Slice = 64 ch = 2.56 MB table slice (< 4MB XCD L2), pinned to XCD via bid&7 (FETCH
// 177->21 MB verified R8/R12). R13 restructure vs R12: a wave = 8 groups x 8 lanes;
// group g owns ONE node's slice entirely (lane = 8 ch), iterating its edge list with
// u16x8 loads batched 4-deep -> NO cross-lane reduce, epair loads are 8-lane broadcasts,
// 8x fewer waves (R12 was issue-bound on reduce/setup overhead: VALUBusy 70%, HBM 8%).
// Cost: edge-loop divergence across groups (max-of-8 deg ~ 1.5x mean) -- net win.
template <int C, int SLICES>
__global__ __launch_bounds__(256) void gather_agg_kernel(
        const u16* __restrict__ h, const int2* __restrict__ epair,
        const int* __restrict__ row_ptr, const float* __restrict__ dinv,
        u16* __restrict__ z, int N) {
    int bid = blockIdx.x;
    int nb, s;
    if (SLICES == 8) {          // slice = XCD
        nb = bid >> 3;
        s = bid & 7;
    } else {                    // SLICES == 4: slice on XCD pair {2s,2s+1}
        nb = (bid >> 3) * 2 + (bid & 1);
        s = (bid & 7) >> 1;
    }
    int t = threadIdx.x;
    int grp = t >> 3;   // node within block, 0..31
    int u = t & 7;      // channel octet within slice
    int n = nb * 32 + grp;
    bool alive = (n < N);
    int nn = alive ? n : (N - 1);
    float dn = dinv[nn];
    const u16* hbase = h + s * 64 + u * 8;  // + row*C
    float acc[8];
    {
        u16x8 ws = *(const u16x8*)(hbase + (size_t)nn * C);
        float sf = dn * dn;
#pragma unroll
        for (int j = 0; j < 8; ++j) acc[j] = bf2f(ws[j]) * sf;
    }
    int e0 = row_ptr[nn];
    int e1 = alive ? row_ptr[nn + 1] : e0;
    int e = e0;
    for (; e + 4 <= e1; e += 4) {
        int2 p0 = epair[e + 0], p1 = epair[e + 1], p2 = epair[e + 2], p3 = epair[e + 3];
        u16x8 w0 = *(const u16x8*)(hbase + (size_t)p0.x * C);
        u16x8 w1 = *(const u16x8*)(hbase + (size_t)p1.x * C);
        u16x8 w2 = *(const u16x8*)(hbase + (size_t)p2.x * C);
        u16x8 w3 = *(const u16x8*)(hbase + (size_t)p3.x * C);
        float n0 = __int_as_float(p0.y) * dn, n1 = __int_as_float(p1.y) * dn;
        float n2 = __int_as_float(p2.y) * dn, n3 = __int_as_float(p3.y) * dn;
#pragma unroll
        for (int j = 0; j < 8; ++j) {
            acc[j] = fmaf(bf2f(w0[j]), n0, acc[j]);
            acc[j] = fmaf(bf2f(w1[j]), n1, acc[j]);
            acc[j] = fmaf(bf2f(w2[j]), n2, acc[j]);
            acc[j] = fmaf(bf2f(w3[j]), n3, acc[j]);
        }
    }
    for (; e < e1; ++e) {
        int2 p = epair[e];
        u16x8 w = *(const u16x8*)(hbase + (size_t)p.x * C);
        float nr = __int_as_float(p.y) * dn;
#pragma unroll
        for (int j = 0; j < 8; ++j) acc[j] = fmaf(bf2f(w[j]), nr, acc[j]);
    }
    if (alive) {
        u16x8 vh;
#pragma unroll
        for (int j = 0; j < 8; ++j) vh[j] = f2bf(acc[j]);
        *(u16x8*)(z + (size_t)n * C + s * 64 + u * 8) = vh;
    }
}

// ---------------------------------------------------------------- 2-term split-bf16 MFMA GEMM
// C = A_hi @ (B_hi + B_lo) + bias;  B transposed [N][K].  BM=128, BN=128, BK=32; 8 waves
// (2x4 of 64x32); TRIPLE-buffered LDS (3 x 24KB = 72KB -> 2 blocks/CU, 16 waves/CU).
// 2-deep prefetch: stage(t+2) issued at iter t; vmcnt(6) waits only on loads issued TWO
// compute phases ago. LDS swizzle: slot ^= (row>>1)&3 (R7-measured: 0 conflicts).
template <int K, bool RELU, bool OUT_BF16>
__global__ __launch_bounds__(512, 4) void gemm_mfma_kernel(
        const u16* __restrict__ A, const u16* __restrict__ Bh, const u16* __restrict__ Bl,
        const float* __restrict__ bias, void* __restrict__ Cout, int M, int N) {
    // per buffer (bytes): A@0 (8K), Bh@8192 (8K), Bl@16384 (8K) = 24KB
    __shared__ u16 lds[3][12288];
    const int tid = threadIdx.x;
    const int lane = tid & 63;
    const int wid = tid >> 6;  // 0..7

    // bijective XCD-chunked swizzle (m204)
    const int nmt = (M + 127) / 128;
    const int total = nmt * 4;
    int bid = blockIdx.x;
    int q = total >> 3, r = total & 7;
    int xcd = bid & 7, pp = bid >> 3;
    int lin = (xcd < r) ? (xcd * (q + 1) + pp) : (r * (q + 1) + (xcd - r) * q + pp);
    const int bm = (lin >> 2) * 128;
    const int bn = (lin & 3) * 128;

    const int wm = (wid & 1) * 64;   // 2 wave-rows
    const int wn = (wid >> 1) * 32;  // 4 wave-cols

    f32x4 acc[4][2];
#pragma unroll
    for (int i = 0; i < 4; ++i)
#pragma unroll
        for (int j = 0; j < 2; ++j) acc[i][j] = (f32x4){0.f, 0.f, 0.f, 0.f};

    // staging: per plane 512 chunks of 16B; wave w covers region [w*64, w*64+64) chunks.
    const int srow = (wid << 4) + (lane >> 2);  // 0..127
    const int scb = (((lane & 3) ^ ((lane >> 3) & 3)) << 4);
    const char* srcA  = (const char*)(A  + (size_t)min(bm + srow, M - 1) * K) + scb;
    const char* srcBh = (const char*)(Bh + (size_t)(bn + srow) * K) + scb;
    const char* srcBl = (const char*)(Bl + (size_t)(bn + srow) * K) + scb;
    const int dstoff = wid << 10;  // wave-uniform (HW adds lane*16)

#define GLL(srcp, dstb)                                                                  \
    __builtin_amdgcn_global_load_lds(                                                    \
        (const __attribute__((address_space(1))) void*)(srcp),                           \
        (__attribute__((address_space(3))) void*)((char*)&lds[buf][0] + (dstb)), 16, 0, 0)

#define STAGE(bufv, k0)                                                                  \
    do {                                                                                 \
        int buf = (bufv);                                                                \
        size_t kb2 = (size_t)(k0) * 2;                                                   \
        GLL(srcA + kb2, dstoff);                                                         \
        GLL(srcBh + kb2, 8192 + dstoff);                                                 \
        GLL(srcBl + kb2, 16384 + dstoff);                                                \
    } while (0)

    STAGE(0, 0);
    STAGE(1, 32);

    const int NT = K / 32;
    const int kb = (lane >> 4) << 4;  // fragment k byte-offset within 64B row
#pragma unroll
    for (int t = 0; t < NT; ++t) {
        if (t + 2 < NT) {
            STAGE((t + 2) % 3, (t + 2) * 32);
            asm volatile("s_waitcnt vmcnt(6)" ::: "memory");  // stage-t done; t+1,t+2 in flight
        } else if (t + 1 < NT) {
            asm volatile("s_waitcnt vmcnt(3)" ::: "memory");
        } else {
            asm volatile("s_waitcnt vmcnt(0)" ::: "memory");
        }
        __builtin_amdgcn_s_barrier();   // all waves: buf[t%3] fully populated
        asm volatile("" ::: "memory");

        const char* L = (const char*)&lds[t % 3][0];
        bf16x8 a[4], b_h[2], b_l[2];
#pragma unroll
        for (int i = 0; i < 4; ++i) {
            int ra = wm + i * 16 + (lane & 15);
            int off = ra * 64 + (kb ^ (((ra >> 1) & 3) << 4));
            a[i] = *(const bf16x8*)(L + off);
        }
#pragma unroll
        for (int j = 0; j < 2; ++j) {
            int rb = wn + j * 16 + (lane & 15);
            int off = rb * 64 + (kb ^ (((rb >> 1) & 3) << 4));
            b_h[j] = *(const bf16x8*)(L + 8192 + off);
            b_l[j] = *(const bf16x8*)(L + 16384 + off);
        }
#pragma unroll
        for (int i = 0; i < 4; ++i)
#pragma unroll
            for (int j = 0; j < 2; ++j) {
                acc[i][j] = __builtin_amdgcn_mfma_f32_16x16x32_bf16(a[i], b_h[j], acc[i][j], 0, 0, 0);
                acc[i][j] = __builtin_amdgcn_mfma_f32_16x16x32_bf16(a[i], b_l[j], acc[i][j], 0, 0, 0);
            }
        asm volatile("" ::: "memory");
        __builtin_amdgcn_s_barrier();   // all waves done reading buf[t%3]
    }
#undef STAGE
#undef GLL

    // epilogue: C/D layout col=lane&15, row=(lane>>4)*4+t  (m89/m91 verified)
#pragma unroll
    for (int j = 0; j < 2; ++j) {
        int gc = bn + wn + j * 16 + (lane & 15);
        float bv = bias[gc];
#pragma unroll
        for (int i = 0; i < 4; ++i) {
#pragma unroll
            for (int t = 0; t < 4; ++t) {
                int gr = bm + wm + i * 16 + ((lane >> 4) << 2) + t;
                if (gr < M) {
                    float v = acc[i][j][t] + bv;
                    if (RELU) v = fmaxf(v, 0.f);
                    if (OUT_BF16)
                        ((u16*)Cout)[(size_t)gr * N + gc] = f2bf(v);
                    else
                        ((float*)Cout)[(size_t)gr * N + gc] = v;
                }
            }
        }
    }
}

// ---------------------------------------------------------------- launch
extern "C" void kernel_launch(void* const* d_in, const int* in_sizes, int n_in,
                              void* d_out, int out_size, void* d_ws, size_t ws_size,
                              hipStream_t stream) {
    const float* x  = (const float*)d_in[0];
    const int*   ei = (const int*)d_in[1];
    const float* W1 = (const float*)d_in[2];
    const float* b1 = (const float*)d_in[3];
    const float* W2 = (const float*)d_in[4];
    const float* b2 = (const float*)d_in[5];
    const int* src = ei;
    const int* dst = ei + N_EDGES;

    char* ws = (char*)d_ws;
    size_t off = 0;
    auto alloc = [&](size_t bytes) {
        void* p = ws + off;
        off = (off + bytes + 255) & ~(size_t)255;
        return p;
    };
    int*   deg     = (int*)alloc(N_NODES * 4);  // reused as cursor
    int*   row_ptr = (int*)alloc((N_NODES + 1) * 4);
    float* dinv    = (float*)alloc(N_NODES * 4);
    int2*  epair   = (int2*)alloc((size_t)N_EDGES * 8);
    u16*   wt1_hi  = (u16*)alloc((size_t)IN_CH * HID_CH * 2);
    u16*   wt1_lo  = (u16*)alloc((size_t)IN_CH * HID_CH * 2);
    u16*   wt2_hi  = (u16*)alloc((size_t)HID_CH * HID_CH * 2);
    u16*   wt2_lo  = (u16*)alloc((size_t)HID_CH * HID_CH * 2);
    u16*   xb      = (u16*)alloc((size_t)N_NODES * IN_CH * 2);   // [N, 256] bf16
    u16*   z1      = (u16*)alloc((size_t)N_NODES * IN_CH * 2);   // [N, 256] bf16 (hi only)
    u16*   z2      = (u16*)alloc((size_t)N_NODES * HID_CH * 2);  // [N, 512] bf16 (hi only)
    u16*   h1      = (u16*)d_out;  // bf16 h1 scratch in d_out (dead before final GEMM writes)

    // CSR + dinv + epair
    hipMemsetAsync(deg, 0, N_NODES * 4, stream);
    count_deg_kernel<<<(N_EDGES + 255) / 256, 256, 0, stream>>>(dst, deg, N_EDGES);
    scan_kernel<<<1, 256, 0, stream>>>(deg, row_ptr, dinv, N_NODES);
    hipMemsetAsync(deg, 0, N_NODES * 4, stream);  // deg -> cursor
    scatter_edges_kernel<<<(N_EDGES + 255) / 256, 256, 0, stream>>>(src, dst, row_ptr, deg, dinv,
                                                                    epair, N_EDGES);

    // conversions
    f32_to_bf16_kernel<<<(N_NODES * IN_CH / 4 + 255) / 256, 256, 0, stream>>>(
        x, xb, N_NODES * IN_CH / 4);
    convert_w_kernel<<<96, 256, 0, stream>>>(W1, wt1_hi, wt1_lo, W2, wt2_hi, wt2_lo);

    const int NMT = (N_NODES + 127) / 128;  // 157 -> grid 628
    const int NB32 = (N_NODES + 31) / 32;   // 625 node-blocks of 32
    // layer 1: z1 = P @ xb (4 slices on XCD pairs) ; h1 = relu(z1 @ (W1h+W1l) + b1) (bf16 out)
    gather_agg_kernel<IN_CH, 4><<<((NB32 + 1) / 2) * 8, 256, 0, stream>>>(
        xb, epair, row_ptr, dinv, z1, N_NODES);
    gemm_mfma_kernel<IN_CH, true, true><<<NMT * 4, 512, 0, stream>>>(
        z1, wt1_hi, wt1_lo, b1, h1, N_NODES, HID_CH);

    // layer 2: z2 = P @ h1 (8 slices, one per XCD) ; out = z2 @ (W2h+W2l) + b2 (fp32 out)
    gather_agg_kernel<HID_CH, 8><<<NB32 * 8, 256, 0, stream>>>(
        h1, epair, row_ptr, dinv, z2, N_NODES);
    gemm_mfma_kernel<HID_CH, false, false><<<NMT * 4, 512, 0, stream>>>(
        z2, wt2_hi, wt2_lo, b2, (float*)d_out, N_NODES, HID_CH);
}

// Round 14
// 166.571 us; speedup vs baseline: 1.6949x; 1.3028x over previous
//
#include <hip/hip_runtime.h>

#define N_NODES 20000
#define N_EDGES 320000
#define IN_CH 256
#define HID_CH 512
#define NB_SCAN ((N_NODES + 255) / 256)  // 79

typedef unsigned short u16;
typedef __attribute__((ext_vector_type(4))) float f32x4;
typedef __attribute__((ext_vector_type(8))) short bf16x8;
typedef __attribute__((ext_vector_type(4))) u16 u16x4;
typedef __attribute__((ext_vector_type(8))) u16 u16x8;

__device__ __forceinline__ float bf2f(u16 h) { return __uint_as_float((unsigned)h << 16); }
__device__ __forceinline__ u16 f2bf(float f) {  // round-to-nearest-even
    unsigned u = __float_as_uint(f);
    return (u16)((u + 0x7fffu + ((u >> 16) & 1u)) >> 16);
}

// ---------------------------------------------------------------- CSR build
__global__ void count_deg_kernel(const int* __restrict__ dst, int* __restrict__ deg, int E) {
    int i = blockIdx.x * blockDim.x + threadIdx.x;
    if (i < E) atomicAdd(&deg[dst[i]], 1);
}

// pass 1: per-block reduce of deg -> bsum, fused dinv = rsqrt(deg+1)
__global__ __launch_bounds__(256) void scan_pass1(const int* __restrict__ deg,
                                                  float* __restrict__ dinv,
                                                  int* __restrict__ bsum, int N) {
    __shared__ int tmp[256];
    int t = threadIdx.x;
    int i = blockIdx.x * 256 + t;
    int d = (i < N) ? deg[i] : 0;
    if (i < N) dinv[i] = rsqrtf((float)d + 1.0f);
    tmp[t] = d;
    __syncthreads();
#pragma unroll
    for (int off = 128; off > 0; off >>= 1) {
        if (t < off) tmp[t] += tmp[t + off];
        __syncthreads();
    }
    if (t == 0) bsum[blockIdx.x] = tmp[0];
}

// pass 2: single small block — exclusive scan over the NB_SCAN block sums
__global__ __launch_bounds__(128) void scan_pass2(int* __restrict__ bsum, int NB) {
    __shared__ int tmp[128];
    int t = threadIdx.x;
    tmp[t] = (t < NB) ? bsum[t] : 0;
    __syncthreads();
#pragma unroll
    for (int off = 1; off < 128; off <<= 1) {
        int v = (t >= off) ? tmp[t - off] : 0;
        __syncthreads();
        tmp[t] += v;
        __syncthreads();
    }
    if (t < NB) bsum[t] = (t == 0) ? 0 : tmp[t - 1];
}

// pass 3: block-local exclusive scan + bsum offset -> row_ptr
__global__ __launch_bounds__(256) void scan_pass3(const int* __restrict__ deg,
                                                  const int* __restrict__ bsum,
                                                  int* __restrict__ row_ptr, int N, int E) {
    __shared__ int tmp[256];
    int t = threadIdx.x;
    int i = blockIdx.x * 256 + t;
    int d = (i < N) ? deg[i] : 0;
    tmp[t] = d;
    __syncthreads();
#pragma unroll
    for (int off = 1; off < 256; off <<= 1) {
        int v = (t >= off) ? tmp[t - off] : 0;
        __syncthreads();
        tmp[t] += v;
        __syncthreads();
    }
    if (i < N) row_ptr[i] = bsum[blockIdx.x] + tmp[t] - d;
    if (i == 0) row_ptr[N] = E;
}

// bucket-scatter: epair[pos] = {src, bits(dinv[src])}
__global__ void scatter_edges_kernel(const int* __restrict__ src, const int* __restrict__ dst,
                                     const int* __restrict__ row_ptr, int* __restrict__ cursor,
                                     const float* __restrict__ dinv, int2* __restrict__ epair,
                                     int E) {
    int e = blockIdx.x * blockDim.x + threadIdx.x;
    if (e >= E) return;
    int d = dst[e];
    int s = src[e];
    int pos = row_ptr[d] + atomicAdd(&cursor[d], 1);
    epair[pos] = make_int2(s, __float_as_int(dinv[s]));
}

// ---------------------------------------------------------------- conversions
__global__ void f32_to_bf16_kernel(const float* __restrict__ in, u16* __restrict__ out, int n4) {
    int i = blockIdx.x * blockDim.x + threadIdx.x;
    if (i >= n4) return;
    float4 v = ((const float4*)in)[i];
    u16x4 o = {f2bf(v.x), f2bf(v.y), f2bf(v.z), f2bf(v.w)};
    ((u16x4*)out)[i] = o;
}

// both weights: W [K][N] f32 -> Wt hi/lo [N][K] bf16 (LDS-tiled transpose + split)
__global__ __launch_bounds__(256) void convert_w_kernel(const float* __restrict__ W1,
                                                        u16* __restrict__ hi1, u16* __restrict__ lo1,
                                                        const float* __restrict__ W2,
                                                        u16* __restrict__ hi2, u16* __restrict__ lo2) {
    __shared__ float t[64][65];
    int b = blockIdx.x;
    const float* W;
    u16 *hi, *lo;
    int K;
    if (b < 32) { W = W1; hi = hi1; lo = lo1; K = IN_CH; }
    else        { b -= 32; W = W2; hi = hi2; lo = lo2; K = HID_CH; }
    const int N = HID_CH;
    int k0 = (b >> 3) * 64, n0 = (b & 7) * 64;
    int c = threadIdx.x & 63, r4 = threadIdx.x >> 6;
#pragma unroll
    for (int i = 0; i < 16; ++i) {
        int r = i * 4 + r4;
        t[r][c] = W[(size_t)(k0 + r) * N + n0 + c];
    }
    __syncthreads();
#pragma unroll
    for (int i = 0; i < 16; ++i) {
        int n = i * 4 + r4;
        float f = t[c][n];
        u16 hb = f2bf(f);
        size_t o = (size_t)(n0 + n) * K + k0 + c;
        hi[o] = hb;
        lo[o] = f2bf(f - bf2f(hb));
    }
}

// ---------------------------------------------------------------- XCD-sliced gather, group-per-node
// z[n] = h[n]*dinv[n]^2 + sum_e h[src]*norm_e*dinv[n]
// Slice = 64 ch = 2.56 MB table slice (< 4MB XCD L2), pinned to XCD via bid&7 (FETCH
// 177->21 MB verified R8/R12). Wave = 8 groups x 8 lanes; group owns ONE node's slice
// (lane = 8 ch), u16x8 loads 4-deep -> no cross-lane reduce (R13-verified structure).
template <int C, int SLICES>
__global__ __launch_bounds__(256) void gather_agg_kernel(
        const u16* __restrict__ h, const int2* __restrict__ epair,
        const int* __restrict__ row_ptr, const float* __restrict__ dinv,
        u16* __restrict__ z, int N) {
    int bid = blockIdx.x;
    int nb, s;
    if (SLICES == 8) {          // slice = XCD
        nb = bid >> 3;
        s = bid & 7;
    } else {                    // SLICES == 4: slice on XCD pair {2s,2s+1}
        nb = (bid >> 3) * 2 + (bid & 1);
        s = (bid & 7) >> 1;
    }
    int t = threadIdx.x;
    int grp = t >> 3;   // node within block, 0..31
    int u = t & 7;      // channel octet within slice
    int n = nb * 32 + grp;
    bool alive = (n < N);
    int nn = alive ? n : (N - 1);
    float dn = dinv[nn];
    const u16* hbase = h + s * 64 + u * 8;  // + row*C
    float acc[8];
    {
        u16x8 ws = *(const u16x8*)(hbase + (size_t)nn * C);
        float sf = dn * dn;
#pragma unroll
        for (int j = 0; j < 8; ++j) acc[j] = bf2f(ws[j]) * sf;
    }
    int e0 = row_ptr[nn];
    int e1 = alive ? row_ptr[nn + 1] : e0;
    int e = e0;
    for (; e + 4 <= e1; e += 4) {
        int2 p0 = epair[e + 0], p1 = epair[e + 1], p2 = epair[e + 2], p3 = epair[e + 3];
        u16x8 w0 = *(const u16x8*)(hbase + (size_t)p0.x * C);
        u16x8 w1 = *(const u16x8*)(hbase + (size_t)p1.x * C);
        u16x8 w2 = *(const u16x8*)(hbase + (size_t)p2.x * C);
        u16x8 w3 = *(const u16x8*)(hbase + (size_t)p3.x * C);
        float n0 = __int_as_float(p0.y) * dn, n1 = __int_as_float(p1.y) * dn;
        float n2 = __int_as_float(p2.y) * dn, n3 = __int_as_float(p3.y) * dn;
#pragma unroll
        for (int j = 0; j < 8; ++j) {
            acc[j] = fmaf(bf2f(w0[j]), n0, acc[j]);
            acc[j] = fmaf(bf2f(w1[j]), n1, acc[j]);
            acc[j] = fmaf(bf2f(w2[j]), n2, acc[j]);
            acc[j] = fmaf(bf2f(w3[j]), n3, acc[j]);
        }
    }
    for (; e < e1; ++e) {
        int2 p = epair[e];
        u16x8 w = *(const u16x8*)(hbase + (size_t)p.x * C);
        float nr = __int_as_float(p.y) * dn;
#pragma unroll
        for (int j = 0; j < 8; ++j) acc[j] = fmaf(bf2f(w[j]), nr, acc[j]);
    }
    if (alive) {
        u16x8 vh;
#pragma unroll
        for (int j = 0; j < 8; ++j) vh[j] = f2bf(acc[j]);
        *(u16x8*)(z + (size_t)n * C + s * 64 + u * 8) = vh;
    }
}

// ---------------------------------------------------------------- 2-term split-bf16 MFMA GEMM
// C = A_hi @ (B_hi + B_lo) + bias;  B transposed [N][K].  BM=128, BN=128, BK=32; 8 waves
// (2x4 of 64x32); TRIPLE-buffered LDS (3 x 24KB = 72KB -> 2 blocks/CU, 16 waves/CU).
// 2-deep prefetch: stage(t+2) issued at iter t; vmcnt(6) waits only on loads issued TWO
// compute phases ago. LDS swizzle: slot ^= (row>>1)&3 (R7-measured: 0 conflicts).
template <int K, bool RELU, bool OUT_BF16>
__global__ __launch_bounds__(512, 4) void gemm_mfma_kernel(
        const u16* __restrict__ A, const u16* __restrict__ Bh, const u16* __restrict__ Bl,
        const float* __restrict__ bias, void* __restrict__ Cout, int M, int N) {
    // per buffer (bytes): A@0 (8K), Bh@8192 (8K), Bl@16384 (8K) = 24KB
    __shared__ u16 lds[3][12288];
    const int tid = threadIdx.x;
    const int lane = tid & 63;
    const int wid = tid >> 6;  // 0..7

    // bijective XCD-chunked swizzle (m204)
    const int nmt = (M + 127) / 128;
    const int total = nmt * 4;
    int bid = blockIdx.x;
    int q = total >> 3, r = total & 7;
    int xcd = bid & 7, pp = bid >> 3;
    int lin = (xcd < r) ? (xcd * (q + 1) + pp) : (r * (q + 1) + (xcd - r) * q + pp);
    const int bm = (lin >> 2) * 128;
    const int bn = (lin & 3) * 128;

    const int wm = (wid & 1) * 64;   // 2 wave-rows
    const int wn = (wid >> 1) * 32;  // 4 wave-cols

    f32x4 acc[4][2];
#pragma unroll
    for (int i = 0; i < 4; ++i)
#pragma unroll
        for (int j = 0; j < 2; ++j) acc[i][j] = (f32x4){0.f, 0.f, 0.f, 0.f};

    // staging: per plane 512 chunks of 16B; wave w covers region [w*64, w*64+64) chunks.
    const int srow = (wid << 4) + (lane >> 2);  // 0..127
    const int scb = (((lane & 3) ^ ((lane >> 3) & 3)) << 4);
    const char* srcA  = (const char*)(A  + (size_t)min(bm + srow, M - 1) * K) + scb;
    const char* srcBh = (const char*)(Bh + (size_t)(bn + srow) * K) + scb;
    const char* srcBl = (const char*)(Bl + (size_t)(bn + srow) * K) + scb;
    const int dstoff = wid << 10;  // wave-uniform (HW adds lane*16)

#define GLL(srcp, dstb)                                                                  \
    __builtin_amdgcn_global_load_lds(                                                    \
        (const __attribute__((address_space(1))) void*)(srcp),                           \
        (__attribute__((address_space(3))) void*)((char*)&lds[buf][0] + (dstb)), 16, 0, 0)

#define STAGE(bufv, k0)                                                                  \
    do {                                                                                 \
        int buf = (bufv);                                                                \
        size_t kb2 = (size_t)(k0) * 2;                                                   \
        GLL(srcA + kb2, dstoff);                                                         \
        GLL(srcBh + kb2, 8192 + dstoff);                                                 \
        GLL(srcBl + kb2, 16384 + dstoff);                                                \
    } while (0)

    STAGE(0, 0);
    STAGE(1, 32);

    const int NT = K / 32;
    const int kb = (lane >> 4) << 4;  // fragment k byte-offset within 64B row
#pragma unroll
    for (int t = 0; t < NT; ++t) {
        if (t + 2 < NT) {
            STAGE((t + 2) % 3, (t + 2) * 32);
            asm volatile("s_waitcnt vmcnt(6)" ::: "memory");  // stage-t done; t+1,t+2 in flight
        } else if (t + 1 < NT) {
            asm volatile("s_waitcnt vmcnt(3)" ::: "memory");
        } else {
            asm volatile("s_waitcnt vmcnt(0)" ::: "memory");
        }
        __builtin_amdgcn_s_barrier();   // all waves: buf[t%3] fully populated
        asm volatile("" ::: "memory");

        const char* L = (const char*)&lds[t % 3][0];
        bf16x8 a[4], b_h[2], b_l[2];
#pragma unroll
        for (int i = 0; i < 4; ++i) {
            int ra = wm + i * 16 + (lane & 15);
            int off = ra * 64 + (kb ^ (((ra >> 1) & 3) << 4));
            a[i] = *(const bf16x8*)(L + off);
        }
#pragma unroll
        for (int j = 0; j < 2; ++j) {
            int rb = wn + j * 16 + (lane & 15);
            int off = rb * 64 + (kb ^ (((rb >> 1) & 3) << 4));
            b_h[j] = *(const bf16x8*)(L + 8192 + off);
            b_l[j] = *(const bf16x8*)(L + 16384 + off);
        }
#pragma unroll
        for (int i = 0; i < 4; ++i)
#pragma unroll
            for (int j = 0; j < 2; ++j) {
                acc[i][j] = __builtin_amdgcn_mfma_f32_16x16x32_bf16(a[i], b_h[j], acc[i][j], 0, 0, 0);
                acc[i][j] = __builtin_amdgcn_mfma_f32_16x16x32_bf16(a[i], b_l[j], acc[i][j], 0, 0, 0);
            }
        asm volatile("" ::: "memory");
        __builtin_amdgcn_s_barrier();   // all waves done reading buf[t%3]
    }
#undef STAGE
#undef GLL

    // epilogue: C/D layout col=lane&15, row=(lane>>4)*4+t  (m89/m91 verified)
#pragma unroll
    for (int j = 0; j < 2; ++j) {
        int gc = bn + wn + j * 16 + (lane & 15);
        float bv = bias[gc];
#pragma unroll
        for (int i = 0; i < 4; ++i) {
#pragma unroll
            for (int t = 0; t < 4; ++t) {
                int gr = bm + wm + i * 16 + ((lane >> 4) << 2) + t;
                if (gr < M) {
                    float v = acc[i][j][t] + bv;
                    if (RELU) v = fmaxf(v, 0.f);
                    if (OUT_BF16)
                        ((u16*)Cout)[(size_t)gr * N + gc] = f2bf(v);
                    else
                        ((float*)Cout)[(size_t)gr * N + gc] = v;
                }
            }
        }
    }
}

// ---------------------------------------------------------------- launch
extern "C" void kernel_launch(void* const* d_in, const int* in_sizes, int n_in,
                              void* d_out, int out_size, void* d_ws, size_t ws_size,
                              hipStream_t stream) {
    const float* x  = (const float*)d_in[0];
    const int*   ei = (const int*)d_in[1];
    const float* W1 = (const float*)d_in[2];
    const float* b1 = (const float*)d_in[3];
    const float* W2 = (const float*)d_in[4];
    const float* b2 = (const float*)d_in[5];
    const int* src = ei;
    const int* dst = ei + N_EDGES;

    char* ws = (char*)d_ws;
    size_t off = 0;
    auto alloc = [&](size_t bytes) {
        void* p = ws + off;
        off = (off + bytes + 255) & ~(size_t)255;
        return p;
    };
    int*   deg     = (int*)alloc(N_NODES * 4);  // reused as cursor
    int*   row_ptr = (int*)alloc((N_NODES + 1) * 4);
    float* dinv    = (float*)alloc(N_NODES * 4);
    int*   bsum    = (int*)alloc(NB_SCAN * 4);
    int2*  epair   = (int2*)alloc((size_t)N_EDGES * 8);
    u16*   wt1_hi  = (u16*)alloc((size_t)IN_CH * HID_CH * 2);
    u16*   wt1_lo  = (u16*)alloc((size_t)IN_CH * HID_CH * 2);
    u16*   wt2_hi  = (u16*)alloc((size_t)HID_CH * HID_CH * 2);
    u16*   wt2_lo  = (u16*)alloc((size_t)HID_CH * HID_CH * 2);
    u16*   xb      = (u16*)alloc((size_t)N_NODES * IN_CH * 2);   // [N, 256] bf16
    u16*   z1      = (u16*)alloc((size_t)N_NODES * IN_CH * 2);   // [N, 256] bf16 (hi only)
    u16*   z2      = (u16*)alloc((size_t)N_NODES * HID_CH * 2);  // [N, 512] bf16 (hi only)
    u16*   h1      = (u16*)d_out;  // bf16 h1 scratch in d_out (dead before final GEMM writes)

    // CSR + dinv + epair  (3-pass parallel scan; R13's single-block scan was 60us on 1 CU)
    hipMemsetAsync(deg, 0, N_NODES * 4, stream);
    count_deg_kernel<<<(N_EDGES + 255) / 256, 256, 0, stream>>>(dst, deg, N_EDGES);
    scan_pass1<<<NB_SCAN, 256, 0, stream>>>(deg, dinv, bsum, N_NODES);
    scan_pass2<<<1, 128, 0, stream>>>(bsum, NB_SCAN);
    scan_pass3<<<NB_SCAN, 256, 0, stream>>>(deg, bsum, row_ptr, N_NODES, N_EDGES);
    hipMemsetAsync(deg, 0, N_NODES * 4, stream);  // deg -> cursor
    scatter_edges_kernel<<<(N_EDGES + 255) / 256, 256, 0, stream>>>(src, dst, row_ptr, deg, dinv,
                                                                    epair, N_EDGES);

    // conversions
    f32_to_bf16_kernel<<<(N_NODES * IN_CH / 4 + 255) / 256, 256, 0, stream>>>(
        x, xb, N_NODES * IN_CH / 4);
    convert_w_kernel<<<96, 256, 0, stream>>>(W1, wt1_hi, wt1_lo, W2, wt2_hi, wt2_lo);

    const int NMT = (N_NODES + 127) / 128;  // 157 -> grid 628
    const int NB32 = (N_NODES + 31) / 32;   // 625 node-blocks of 32
    // layer 1: z1 = P @ xb (4 slices on XCD pairs) ; h1 = relu(z1 @ (W1h+W1l) + b1) (bf16 out)
    gather_agg_kernel<IN_CH, 4><<<((NB32 + 1) / 2) * 8, 256, 0, stream>>>(
        xb, epair, row_ptr, dinv, z1, N_NODES);
    gemm_mfma_kernel<IN_CH, true, true><<<NMT * 4, 512, 0, stream>>>(
        z1, wt1_hi, wt1_lo, b1, h1, N_NODES, HID_CH);

    // layer 2: z2 = P @ h1 (8 slices, one per XCD) ; out = z2 @ (W2h+W2l) + b2 (fp32 out)
    gather_agg_kernel<HID_CH, 8><<<NB32 * 8, 256, 0, stream>>>(
        h1, epair, row_ptr, dinv, z2, N_NODES);
    gemm_mfma_kernel<HID_CH, false, false><<<NMT * 4, 512, 0, stream>>>(
        z2, wt2_hi, wt2_lo, b2, (float*)d_out, N_NODES, HID_CH);
}

// Round 15
// 164.296 us; speedup vs baseline: 1.7184x; 1.0138x over previous
//
#include <hip/hip_runtime.h>

#define N_NODES 20000
#define N_EDGES 320000
#define IN_CH 256
#define HID_CH 512
#define NB_SCAN ((N_NODES + 255) / 256)  // 79

typedef unsigned short u16;
typedef __attribute__((ext_vector_type(4))) float f32x4;
typedef __attribute__((ext_vector_type(8))) short bf16x8;
typedef __attribute__((ext_vector_type(4))) u16 u16x4;
typedef __attribute__((ext_vector_type(8))) u16 u16x8;

__device__ __forceinline__ float bf2f(u16 h) { return __uint_as_float((unsigned)h << 16); }
__device__ __forceinline__ u16 f2bf(float f) {  // round-to-nearest-even
    unsigned u = __float_as_uint(f);
    return (u16)((u + 0x7fffu + ((u >> 16) & 1u)) >> 16);
}

// ---------------------------------------------------------------- CSR build
// custom zero (the runtime's fillBufferAligned measured 43us for 80KB -- R14 profile)
__global__ void zero2_kernel(int* __restrict__ a, int* __restrict__ b, int n) {
    int i = blockIdx.x * blockDim.x + threadIdx.x;
    if (i < n) { a[i] = 0; b[i] = 0; }
}

__global__ void count_deg_kernel(const int* __restrict__ dst, int* __restrict__ deg, int E) {
    int i = blockIdx.x * blockDim.x + threadIdx.x;
    if (i < E) atomicAdd(&deg[dst[i]], 1);
}

// pass 1: per-block reduce of deg -> bsum, fused dinv = rsqrt(deg+1)
__global__ __launch_bounds__(256) void scan_pass1(const int* __restrict__ deg,
                                                  float* __restrict__ dinv,
                                                  int* __restrict__ bsum, int N) {
    __shared__ int tmp[256];
    int t = threadIdx.x;
    int i = blockIdx.x * 256 + t;
    int d = (i < N) ? deg[i] : 0;
    if (i < N) dinv[i] = rsqrtf((float)d + 1.0f);
    tmp[t] = d;
    __syncthreads();
#pragma unroll
    for (int off = 128; off > 0; off >>= 1) {
        if (t < off) tmp[t] += tmp[t + off];
        __syncthreads();
    }
    if (t == 0) bsum[blockIdx.x] = tmp[0];
}

// pass 2: single small block — exclusive scan over the NB_SCAN block sums
__global__ __launch_bounds__(128) void scan_pass2(int* __restrict__ bsum, int NB) {
    __shared__ int tmp[128];
    int t = threadIdx.x;
    tmp[t] = (t < NB) ? bsum[t] : 0;
    __syncthreads();
#pragma unroll
    for (int off = 1; off < 128; off <<= 1) {
        int v = (t >= off) ? tmp[t - off] : 0;
        __syncthreads();
        tmp[t] += v;
        __syncthreads();
    }
    if (t < NB) bsum[t] = (t == 0) ? 0 : tmp[t - 1];
}

// pass 3: block-local exclusive scan + bsum offset -> row_ptr
__global__ __launch_bounds__(256) void scan_pass3(const int* __restrict__ deg,
                                                  const int* __restrict__ bsum,
                                                  int* __restrict__ row_ptr, int N, int E) {
    __shared__ int tmp[256];
    int t = threadIdx.x;
    int i = blockIdx.x * 256 + t;
    int d = (i < N) ? deg[i] : 0;
    tmp[t] = d;
    __syncthreads();
#pragma unroll
    for (int off = 1; off < 256; off <<= 1) {
        int v = (t >= off) ? tmp[t - off] : 0;
        __syncthreads();
        tmp[t] += v;
        __syncthreads();
    }
    if (i < N) row_ptr[i] = bsum[blockIdx.x] + tmp[t] - d;
    if (i == 0) row_ptr[N] = E;
}

// bucket-scatter: epair[pos] = {src, bits(dinv[src])}
__global__ void scatter_edges_kernel(const int* __restrict__ src, const int* __restrict__ dst,
                                     const int* __restrict__ row_ptr, int* __restrict__ cursor,
                                     const float* __restrict__ dinv, int2* __restrict__ epair,
                                     int E) {
    int e = blockIdx.x * blockDim.x + threadIdx.x;
    if (e >= E) return;
    int d = dst[e];
    int s = src[e];
    int pos = row_ptr[d] + atomicAdd(&cursor[d], 1);
    epair[pos] = make_int2(s, __float_as_int(dinv[s]));
}

// ---------------------------------------------------------------- conversions
__global__ void f32_to_bf16_kernel(const float* __restrict__ in, u16* __restrict__ out, int n4) {
    int i = blockIdx.x * blockDim.x + threadIdx.x;
    if (i >= n4) return;
    float4 v = ((const float4*)in)[i];
    u16x4 o = {f2bf(v.x), f2bf(v.y), f2bf(v.z), f2bf(v.w)};
    ((u16x4*)out)[i] = o;
}

// both weights: W [K][N] f32 -> Wt hi/lo [N][K] bf16 (LDS-tiled transpose + split)
__global__ __launch_bounds__(256) void convert_w_kernel(const float* __restrict__ W1,
                                                        u16* __restrict__ hi1, u16* __restrict__ lo1,
                                                        const float* __restrict__ W2,
                                                        u16* __restrict__ hi2, u16* __restrict__ lo2) {
    __shared__ float t[64][65];
    int b = blockIdx.x;
    const float* W;
    u16 *hi, *lo;
    int K;
    if (b < 32) { W = W1; hi = hi1; lo = lo1; K = IN_CH; }
    else        { b -= 32; W = W2; hi = hi2; lo = lo2; K = HID_CH; }
    const int N = HID_CH;
    int k0 = (b >> 3) * 64, n0 = (b & 7) * 64;
    int c = threadIdx.x & 63, r4 = threadIdx.x >> 6;
#pragma unroll
    for (int i = 0; i < 16; ++i) {
        int r = i * 4 + r4;
        t[r][c] = W[(size_t)(k0 + r) * N + n0 + c];
    }
    __syncthreads();
#pragma unroll
    for (int i = 0; i < 16; ++i) {
        int n = i * 4 + r4;
        float f = t[c][n];
        u16 hb = f2bf(f);
        size_t o = (size_t)(n0 + n) * K + k0 + c;
        hi[o] = hb;
        lo[o] = f2bf(f - bf2f(hb));
    }
}

// ---------------------------------------------------------------- XCD-sliced gather, group-per-node
// z[n] = h[n]*dinv[n]^2 + sum_e h[src]*norm_e*dinv[n]
// Slice = 64 ch = 2.56 MB table slice (< 4MB XCD L2), pinned to XCD via bid&7 (FETCH
// 177->21 MB verified R8/R12). Wave = 8 groups x 8 lanes; group owns ONE node's slice
// (lane = 8 ch), u16x8 loads 4-deep -> no cross-lane reduce (R13-verified structure).
template <int C, int SLICES>
__global__ __launch_bounds__(256) void gather_agg_kernel(
        const u16* __restrict__ h, const int2* __restrict__ epair,
        const int* __restrict__ row_ptr, const float* __restrict__ dinv,
        u16* __restrict__ z, int N) {
    int bid = blockIdx.x;
    int nb, s;
    if (SLICES == 8) {          // slice = XCD
        nb = bid >> 3;
        s = bid & 7;
    } else {                    // SLICES == 4: slice on XCD pair {2s,2s+1}
        nb = (bid >> 3) * 2 + (bid & 1);
        s = (bid & 7) >> 1;
    }
    int t = threadIdx.x;
    int grp = t >> 3;   // node within block, 0..31
    int u = t & 7;      // channel octet within slice
    int n = nb * 32 + grp;
    bool alive = (n < N);
    int nn = alive ? n : (N - 1);
    float dn = dinv[nn];
    const u16* hbase = h + s * 64 + u * 8;  // + row*C
    float acc[8];
    {
        u16x8 ws = *(const u16x8*)(hbase + (size_t)nn * C);
        float sf = dn * dn;
#pragma unroll
        for (int j = 0; j < 8; ++j) acc[j] = bf2f(ws[j]) * sf;
    }
    int e0 = row_ptr[nn];
    int e1 = alive ? row_ptr[nn + 1] : e0;
    int e = e0;
    for (; e + 4 <= e1; e += 4) {
        int2 p0 = epair[e + 0], p1 = epair[e + 1], p2 = epair[e + 2], p3 = epair[e + 3];
        u16x8 w0 = *(const u16x8*)(hbase + (size_t)p0.x * C);
        u16x8 w1 = *(const u16x8*)(hbase + (size_t)p1.x * C);
        u16x8 w2 = *(const u16x8*)(hbase + (size_t)p2.x * C);
        u16x8 w3 = *(const u16x8*)(hbase + (size_t)p3.x * C);
        float n0 = __int_as_float(p0.y) * dn, n1 = __int_as_float(p1.y) * dn;
        float n2 = __int_as_float(p2.y) * dn, n3 = __int_as_float(p3.y) * dn;
#pragma unroll
        for (int j = 0; j < 8; ++j) {
            acc[j] = fmaf(bf2f(w0[j]), n0, acc[j]);
            acc[j] = fmaf(bf2f(w1[j]), n1, acc[j]);
            acc[j] = fmaf(bf2f(w2[j]), n2, acc[j]);
            acc[j] = fmaf(bf2f(w3[j]), n3, acc[j]);
        }
    }
    for (; e < e1; ++e) {
        int2 p = epair[e];
        u16x8 w = *(const u16x8*)(hbase + (size_t)p.x * C);
        float nr = __int_as_float(p.y) * dn;
#pragma unroll
        for (int j = 0; j < 8; ++j) acc[j] = fmaf(bf2f(w[j]), nr, acc[j]);
    }
    if (alive) {
        u16x8 vh;
#pragma unroll
        for (int j = 0; j < 8; ++j) vh[j] = f2bf(acc[j]);
        *(u16x8*)(z + (size_t)n * C + s * 64 + u * 8) = vh;
    }
}

// ---------------------------------------------------------------- 2-term split-bf16 MFMA GEMM
// C = A_hi @ (B_hi + B_lo) + bias;  B transposed [N][K].  BM=128, BN=128, BK=32; 8 waves
// (2x4 of 64x32); TRIPLE-buffered LDS (3 x 24KB = 72KB -> 2 blocks/CU, 16 waves/CU).
// R15: SINGLE barrier per K-step. With tbuf, STAGE(t+2) overwrites buf[(t-1)%3]; any wave
// past barrier(t) has ALREADY consumed its iter-(t-1) ds_reads (MFMA data dep forces
// lgkmcnt drain before issue), so the trailing barrier is redundant -> barrier count
// halves and MFMA(t) overlaps STAGE(t+2) issue. vmcnt(3) = wait own stage-t loads only.
template <int K, bool RELU, bool OUT_BF16>
__global__ __launch_bounds__(512, 4) void gemm_mfma_kernel(
        const u16* __restrict__ A, const u16* __restrict__ Bh, const u16* __restrict__ Bl,
        const float* __restrict__ bias, void* __restrict__ Cout, int M, int N) {
    // per buffer (bytes): A@0 (8K), Bh@8192 (8K), Bl@16384 (8K) = 24KB
    __shared__ u16 lds[3][12288];
    const int tid = threadIdx.x;
    const int lane = tid & 63;
    const int wid = tid >> 6;  // 0..7

    // bijective XCD-chunked swizzle (m204)
    const int nmt = (M + 127) / 128;
    const int total = nmt * 4;
    int bid = blockIdx.x;
    int q = total >> 3, r = total & 7;
    int xcd = bid & 7, pp = bid >> 3;
    int lin = (xcd < r) ? (xcd * (q + 1) + pp) : (r * (q + 1) + (xcd - r) * q + pp);
    const int bm = (lin >> 2) * 128;
    const int bn = (lin & 3) * 128;

    const int wm = (wid & 1) * 64;   // 2 wave-rows
    const int wn = (wid >> 1) * 32;  // 4 wave-cols

    f32x4 acc[4][2];
#pragma unroll
    for (int i = 0; i < 4; ++i)
#pragma unroll
        for (int j = 0; j < 2; ++j) acc[i][j] = (f32x4){0.f, 0.f, 0.f, 0.f};

    // staging: per plane 512 chunks of 16B; wave w covers region [w*64, w*64+64) chunks.
    const int srow = (wid << 4) + (lane >> 2);  // 0..127
    const int scb = (((lane & 3) ^ ((lane >> 3) & 3)) << 4);
    const char* srcA  = (const char*)(A  + (size_t)min(bm + srow, M - 1) * K) + scb;
    const char* srcBh = (const char*)(Bh + (size_t)(bn + srow) * K) + scb;
    const char* srcBl = (const char*)(Bl + (size_t)(bn + srow) * K) + scb;
    const int dstoff = wid << 10;  // wave-uniform (HW adds lane*16)

#define GLL(srcp, dstb)                                                                  \
    __builtin_amdgcn_global_load_lds(                                                    \
        (const __attribute__((address_space(1))) void*)(srcp),                           \
        (__attribute__((address_space(3))) void*)((char*)&lds[buf][0] + (dstb)), 16, 0, 0)

#define STAGE(bufv, k0)                                                                  \
    do {                                                                                 \
        int buf = (bufv);                                                                \
        size_t kb2 = (size_t)(k0) * 2;                                                   \
        GLL(srcA + kb2, dstoff);                                                         \
        GLL(srcBh + kb2, 8192 + dstoff);                                                 \
        GLL(srcBl + kb2, 16384 + dstoff);                                                \
    } while (0)

    STAGE(0, 0);
    STAGE(1, 32);

    const int NT = K / 32;
    const int kb = (lane >> 4) << 4;  // fragment k byte-offset within 64B row
#pragma unroll
    for (int t = 0; t < NT; ++t) {
        if (t + 1 < NT) {
            asm volatile("s_waitcnt vmcnt(3)" ::: "memory");  // own stage-t loads done
        } else {
            asm volatile("s_waitcnt vmcnt(0)" ::: "memory");
        }
        __builtin_amdgcn_s_barrier();   // all waves: buf[t%3] populated; all reads of
        asm volatile("" ::: "memory");  // buf[(t-1)%3] consumed (MFMA dep) -> safe to stage

        if (t + 2 < NT) STAGE((t + 2) % 3, (t + 2) * 32);

        const char* L = (const char*)&lds[t % 3][0];
        bf16x8 a[4], b_h[2], b_l[2];
#pragma unroll
        for (int i = 0; i < 4; ++i) {
            int ra = wm + i * 16 + (lane & 15);
            int off = ra * 64 + (kb ^ (((ra >> 1) & 3) << 4));
            a[i] = *(const bf16x8*)(L + off);
        }
#pragma unroll
        for (int j = 0; j < 2; ++j) {
            int rb = wn + j * 16 + (lane & 15);
            int off = rb * 64 + (kb ^ (((rb >> 1) & 3) << 4));
            b_h[j] = *(const bf16x8*)(L + 8192 + off);
            b_l[j] = *(const bf16x8*)(L + 16384 + off);
        }
#pragma unroll
        for (int i = 0; i < 4; ++i)
#pragma unroll
            for (int j = 0; j < 2; ++j) {
                acc[i][j] = __builtin_amdgcn_mfma_f32_16x16x32_bf16(a[i], b_h[j], acc[i][j], 0, 0, 0);
                acc[i][j] = __builtin_amdgcn_mfma_f32_16x16x32_bf16(a[i], b_l[j], acc[i][j], 0, 0, 0);
            }
    }
#undef STAGE
#undef GLL

    // epilogue: C/D layout col=lane&15, row=(lane>>4)*4+t  (m89/m91 verified)
#pragma unroll
    for (int j = 0; j < 2; ++j) {
        int gc = bn + wn + j * 16 + (lane & 15);
        float bv = bias[gc];
#pragma unroll
        for (int i = 0; i < 4; ++i) {
#pragma unroll
            for (int t = 0; t < 4; ++t) {
                int gr = bm + wm + i * 16 + ((lane >> 4) << 2) + t;
                if (gr < M) {
                    float v = acc[i][j][t] + bv;
                    if (RELU) v = fmaxf(v, 0.f);
                    if (OUT_BF16)
                        ((u16*)Cout)[(size_t)gr * N + gc] = f2bf(v);
                    else
                        ((float*)Cout)[(size_t)gr * N + gc] = v;
                }
            }
        }
    }
}

// ---------------------------------------------------------------- launch
extern "C" void kernel_launch(void* const* d_in, const int* in_sizes, int n_in,
                              void* d_out, int out_size, void* d_ws, size_t ws_size,
                              hipStream_t stream) {
    const float* x  = (const float*)d_in[0];
    const int*   ei = (const int*)d_in[1];
    const float* W1 = (const float*)d_in[2];
    const float* b1 = (const float*)d_in[3];
    const float* W2 = (const float*)d_in[4];
    const float* b2 = (const float*)d_in[5];
    const int* src = ei;
    const int* dst = ei + N_EDGES;

    char* ws = (char*)d_ws;
    size_t off = 0;
    auto alloc = [&](size_t bytes) {
        void* p = ws + off;
        off = (off + bytes + 255) & ~(size_t)255;
        return p;
    };
    int*   deg     = (int*)alloc(N_NODES * 4);
    int*   cursor  = (int*)alloc(N_NODES * 4);
    int*   row_ptr = (int*)alloc((N_NODES + 1) * 4);
    float* dinv    = (float*)alloc(N_NODES * 4);
    int*   bsum    = (int*)alloc(NB_SCAN * 4);
    int2*  epair   = (int2*)alloc((size_t)N_EDGES * 8);
    u16*   wt1_hi  = (u16*)alloc((size_t)IN_CH * HID_CH * 2);
    u16*   wt1_lo  = (u16*)alloc((size_t)IN_CH * HID_CH * 2);
    u16*   wt2_hi  = (u16*)alloc((size_t)HID_CH * HID_CH * 2);
    u16*   wt2_lo  = (u16*)alloc((size_t)HID_CH * HID_CH * 2);
    u16*   xb      = (u16*)alloc((size_t)N_NODES * IN_CH * 2);   // [N, 256] bf16
    u16*   z1      = (u16*)alloc((size_t)N_NODES * IN_CH * 2);   // [N, 256] bf16 (hi only)
    u16*   z2      = (u16*)alloc((size_t)N_NODES * HID_CH * 2);  // [N, 512] bf16 (hi only)
    u16*   h1      = (u16*)d_out;  // bf16 h1 scratch in d_out (dead before final GEMM writes)

    // CSR + dinv + epair (custom zero kernel: runtime fill measured 43us for 80KB, R14)
    zero2_kernel<<<NB_SCAN, 256, 0, stream>>>(deg, cursor, N_NODES);
    count_deg_kernel<<<(N_EDGES + 255) / 256, 256, 0, stream>>>(dst, deg, N_EDGES);
    scan_pass1<<<NB_SCAN, 256, 0, stream>>>(deg, dinv, bsum, N_NODES);
    scan_pass2<<<1, 128, 0, stream>>>(bsum, NB_SCAN);
    scan_pass3<<<NB_SCAN, 256, 0, stream>>>(deg, bsum, row_ptr, N_NODES, N_EDGES);
    scatter_edges_kernel<<<(N_EDGES + 255) / 256, 256, 0, stream>>>(src, dst, row_ptr, cursor,
                                                                    dinv, epair, N_EDGES);

    // conversions
    f32_to_bf16_kernel<<<(N_NODES * IN_CH / 4 + 255) / 256, 256, 0, stream>>>(
        x, xb, N_NODES * IN_CH / 4);
    convert_w_kernel<<<96, 256, 0, stream>>>(W1, wt1_hi, wt1_lo, W2, wt2_hi, wt2_lo);

    const int NMT = (N_NODES + 127) / 128;  // 157 -> grid 628
    const int NB32 = (N_NODES + 31) / 32;   // 625 node-blocks of 32
    // layer 1: z1 = P @ xb (4 slices on XCD pairs) ; h1 = relu(z1 @ (W1h+W1l) + b1) (bf16 out)
    gather_agg_kernel<IN_CH, 4><<<((NB32 + 1) / 2) * 8, 256, 0, stream>>>(
        xb, epair, row_ptr, dinv, z1, N_NODES);
    gemm_mfma_kernel<IN_CH, true, true><<<NMT * 4, 512, 0, stream>>>(
        z1, wt1_hi, wt1_lo, b1, h1, N_NODES, HID_CH);

    // layer 2: z2 = P @ h1 (8 slices, one per XCD) ; out = z2 @ (W2h+W2l) + b2 (fp32 out)
    gather_agg_kernel<HID_CH, 8><<<NB32 * 8, 256, 0, stream>>>(
        h1, epair, row_ptr, dinv, z2, N_NODES);
    gemm_mfma_kernel<HID_CH, false, false><<<NMT * 4, 512, 0, stream>>>(
        z2, wt2_hi, wt2_lo, b2, (float*)d_out, N_NODES, HID_CH);
}